// Round 1
// baseline (1178.513 us; speedup 1.0000x reference)
//
#include <hip/hip_runtime.h>
#include <hip/hip_bf16.h>

// Sizes (fixed by the reference)
#define BDIM 2
#define TDIM 1024
#define DDIM 1024
#define HDIM 16
#define HD   64
#define RROWS (BDIM * TDIM)        // 2048 rows for the big GEMMs
#define BH    (BDIM * HDIM)        // 32 (b,h) pairs
#define NHE   (BH * TDIM * HD)     // 2,097,152 elements in head layout
#define NHE4  (NHE / 4)
#define DIFF_BLOCKS 1024
#define KCH 64                     // keys per LDS chunk in attention

struct FState {
  int   cw;
  float temp;
  int   done;
  int   upd;
  int   done_prev;
  float thr;
  float fac;
  int   pad;
};

// ---------------------------------------------------------------------------
// init: scalar state from input scalars
// ---------------------------------------------------------------------------
__global__ void init_kernel(FState* st, const float* thr, const float* tb, const float* fac) {
  if (threadIdx.x == 0 && blockIdx.x == 0) {
    int cw0 = TDIM;                       // max(min(T, 2048), 64) = 1024
    if (cw0 > 2048) cw0 = 2048;
    if (cw0 < 64) cw0 = 64;
    st->cw = cw0;
    st->temp = tb[0];
    st->done = 0;
    st->done_prev = 0;
    st->upd = 1;
    st->thr = thr[0];
    st->fac = fac[0];
  }
}

// ---------------------------------------------------------------------------
// LayerNorm of x with two weight vectors (lna, lnb share mean/var)
// one block per row (1024 elems), 256 threads * float4
// ---------------------------------------------------------------------------
__global__ __launch_bounds__(256) void ln_x_kernel(
    const float* __restrict__ x, const float* __restrict__ wa, const float* __restrict__ wb,
    float* __restrict__ xa, float* __restrict__ xb)
{
  const int row = blockIdx.x;
  const int tid = threadIdx.x;
  const float4 v = reinterpret_cast<const float4*>(x + (size_t)row * DDIM)[tid];
  float s = v.x + v.y + v.z + v.w;
  float q = v.x * v.x + v.y * v.y + v.z * v.z + v.w * v.w;
#pragma unroll
  for (int off = 1; off < 64; off <<= 1) {
    s += __shfl_xor(s, off);
    q += __shfl_xor(q, off);
  }
  __shared__ float ss[4], qq[4];
  const int lane = tid & 63, wv = tid >> 6;
  if (lane == 0) { ss[wv] = s; qq[wv] = q; }
  __syncthreads();
  s = ss[0] + ss[1] + ss[2] + ss[3];
  q = qq[0] + qq[1] + qq[2] + qq[3];
  const float mean = s * (1.0f / DDIM);
  const float var  = q * (1.0f / DDIM) - mean * mean;   // biased var
  const float inv  = rsqrtf(var + 1e-5f);
  const float4 a4 = reinterpret_cast<const float4*>(wa)[tid];
  const float4 b4 = reinterpret_cast<const float4*>(wb)[tid];
  float4 h;
  h.x = (v.x - mean) * inv; h.y = (v.y - mean) * inv;
  h.z = (v.z - mean) * inv; h.w = (v.w - mean) * inv;
  float4 oa, ob;
  oa.x = h.x * a4.x; oa.y = h.y * a4.y; oa.z = h.z * a4.z; oa.w = h.w * a4.w;
  ob.x = h.x * b4.x; ob.y = h.y * b4.y; ob.z = h.z * b4.z; ob.w = h.w * b4.w;
  reinterpret_cast<float4*>(xa + (size_t)row * DDIM)[tid] = oa;
  reinterpret_cast<float4*>(xb + (size_t)row * DDIM)[tid] = ob;
}

// ---------------------------------------------------------------------------
// fp32 tiled GEMM: C = (A @ W^T + bias) * scale
// A: [2048,1024]; W: [1024,1024] row-major (so we need W[n][k]); C: [2048,1024]
// AMODE 0: A row-major.  AMODE 1: A gathered from head layout [B,H,T,64].
// CMODE 0: C row-major.  CMODE 1: C scattered to head layout.
// tile 64x64, BK=16, 256 threads, 4x4 per thread.
// ---------------------------------------------------------------------------
template<int AMODE, int CMODE, bool HASBIAS>
__global__ __launch_bounds__(256) void gemm_bt_kernel(
    const float* __restrict__ A, const float* __restrict__ W,
    const float* __restrict__ bias, float* __restrict__ C, float scale)
{
  __shared__ __align__(16) float As[16][64];
  __shared__ __align__(16) float Ws[16][64];
  const int tid = threadIdx.x;
  const int bm = blockIdx.x;   // 32 blocks of 64 rows
  const int bn = blockIdx.y;   // 16 blocks of 64 cols
  const int ty = tid >> 4, tx = tid & 15;
  float acc[4][4] = {};
  for (int kt = 0; kt < DDIM; kt += 16) {
    __syncthreads();
#pragma unroll
    for (int j = 0; j < 4; ++j) {
      const int idx = tid + j * 256;
      const int kk = idx & 15, mm = idx >> 4;
      const int k = kt + kk;
      const int r = bm * 64 + mm;
      size_t ai;
      if (AMODE == 0) {
        ai = (size_t)r * DDIM + k;
      } else {
        const int b = r >> 10, t = r & (TDIM - 1);
        ai = ((size_t)(b * HDIM + (k >> 6)) * TDIM + t) * HD + (k & 63);
      }
      As[kk][mm] = A[ai];
      const int n = bn * 64 + mm;
      Ws[kk][mm] = W[(size_t)n * DDIM + k];
    }
    __syncthreads();
#pragma unroll
    for (int kk = 0; kk < 16; ++kk) {
      const float4 a = *reinterpret_cast<const float4*>(&As[kk][ty * 4]);
      const float4 w = *reinterpret_cast<const float4*>(&Ws[kk][tx * 4]);
      const float av[4] = {a.x, a.y, a.z, a.w};
      const float wv[4] = {w.x, w.y, w.z, w.w};
#pragma unroll
      for (int i = 0; i < 4; ++i)
#pragma unroll
        for (int j = 0; j < 4; ++j) acc[i][j] += av[i] * wv[j];
    }
  }
#pragma unroll
  for (int i = 0; i < 4; ++i) {
    const int r = bm * 64 + ty * 4 + i;
    const int b = r >> 10, t = r & (TDIM - 1);
#pragma unroll
    for (int j = 0; j < 4; ++j) {
      const int n = bn * 64 + tx * 4 + j;
      float v = acc[i][j];
      if constexpr (HASBIAS) v += bias[n];
      v *= scale;
      size_t ci;
      if (CMODE == 0) ci = (size_t)r * DDIM + n;
      else ci = ((size_t)(b * HDIM + (n >> 6)) * TDIM + t) * HD + (n & 63);
      C[ci] = v;
    }
  }
}

// ---------------------------------------------------------------------------
// per-head 64x64 projection (+optional LN, +optional tscale & window/done gating)
// y[d] = sum_i w[d][i] * h[i] + b[d];  one wave per row, lane = output dim d.
// w staged in LDS transposed (pad 65 to avoid bank conflicts), h broadcast via readlane.
// ---------------------------------------------------------------------------
template<bool DO_LN, bool IS_SQ>
__global__ __launch_bounds__(256) void headproj_kernel(
    const float* __restrict__ in, float* __restrict__ out,
    const float* __restrict__ w, const float* __restrict__ bias,
    const float* __restrict__ lnw, const FState* __restrict__ st)
{
  if constexpr (IS_SQ) { if (st->done) return; }
  __shared__ float wl[64 * 65];
  const int tid = threadIdx.x;
  for (int idx = tid; idx < 4096; idx += 256) {
    const int d = idx >> 6, i = idx & 63;
    wl[i * 65 + d] = w[idx];
  }
  const int lane = tid & 63, wv = tid >> 6;
  const float bd = bias[lane];
  float lw = 1.0f;
  if constexpr (DO_LN) lw = lnw[lane];
  float ts = 1.0f;
  int cw = TDIM;
  if constexpr (IS_SQ) {
    const float tp = st->temp;
    ts = (tp > 0.0f) ? rsqrtf(tp) : 1.0f;
    cw = st->cw;
  }
  __syncthreads();
  const int rowBase = blockIdx.x * 32 + wv * 8;
  for (int rr = 0; rr < 8; ++rr) {
    const int row = rowBase + rr;
    if constexpr (IS_SQ) {
      if ((row & (TDIM - 1)) >= cw) continue;   // rows >= cw never consumed
    }
    const float h = in[(size_t)row * HD + lane];
    float y = bd;
#pragma unroll
    for (int i = 0; i < 64; ++i) {
      const float hv = __uint_as_float((unsigned)__builtin_amdgcn_readlane((int)__float_as_uint(h), i));
      y += wl[i * 65 + lane] * hv;
    }
    if constexpr (DO_LN) {
      float s = y;
#pragma unroll
      for (int off = 1; off < 64; off <<= 1) s += __shfl_xor(s, off);
      const float mean = s * (1.0f / 64.0f);
      const float t0 = y - mean;
      float v2 = t0 * t0;
#pragma unroll
      for (int off = 1; off < 64; off <<= 1) v2 += __shfl_xor(v2, off);
      y = t0 * rsqrtf(v2 * (1.0f / 64.0f) + 1e-5f) * lw;
    }
    if constexpr (IS_SQ) y *= ts;
    out[(size_t)row * HD + lane] = y;
  }
}

// ---------------------------------------------------------------------------
// Flash-style masked attention, fp32.
// Block = 256 threads (4 waves). Wave = 16 q-rows x 4 d-groups (lane = qlocal*4+dg).
// Online softmax with deferred-max (THR=8). Keys/Values chunked 64 at a time in LDS.
// iter_out rows >= cw are written as zeros.
// ---------------------------------------------------------------------------
__global__ __launch_bounds__(256) void attn_kernel(
    const float* __restrict__ sq, const float* __restrict__ sk,
    const float* __restrict__ vp, float* __restrict__ io,
    const FState* __restrict__ st)
{
  if (st->done) return;
  const int cw = st->cw;
  const int bh = blockIdx.y;
  const int tid = threadIdx.x;
  const int lane = tid & 63, wv = tid >> 6;
  const int qlocal = lane >> 2, dg = lane & 3;
  const int qrow = blockIdx.x * 64 + wv * 16 + qlocal;
  const int dg16 = dg * 16;
  const size_t base = (size_t)bh * TDIM * HD;
  float* orow = io + base + (size_t)qrow * HD + dg16;

  if (blockIdx.x * 64 >= cw) {           // whole block out of window: zero + exit
    const float4 z = {0.f, 0.f, 0.f, 0.f};
    float4* o4 = reinterpret_cast<float4*>(orow);
    o4[0] = z; o4[1] = z; o4[2] = z; o4[3] = z;
    return;
  }

  __shared__ __align__(16) float skL[KCH][HD];
  __shared__ __align__(16) float vpL[KCH][HD];

  float4 q4[4];
  {
    const float4* p = reinterpret_cast<const float4*>(sq + base + (size_t)qrow * HD + dg16);
    q4[0] = p[0]; q4[1] = p[1]; q4[2] = p[2]; q4[3] = p[3];
  }
  const bool valid = (qrow < cw);
  float m = 0.0f, l = 0.0f;
  float4 acc[4] = {};

  for (int k0 = 0; k0 < cw; k0 += KCH) {
    const int kmax = min(KCH, cw - k0);
    __syncthreads();
    {
      const float4* gs = reinterpret_cast<const float4*>(sk + base + (size_t)k0 * HD);
      const float4* gv = reinterpret_cast<const float4*>(vp + base + (size_t)k0 * HD);
      float4* ls = reinterpret_cast<float4*>(&skL[0][0]);
      float4* lv = reinterpret_cast<float4*>(&vpL[0][0]);
      const int n4 = kmax * (HD / 4);
      for (int i = tid; i < n4; i += 256) { ls[i] = gs[i]; lv[i] = gv[i]; }
    }
    __syncthreads();
    for (int kk = 0; kk < kmax; ++kk) {
      const float4* kr = reinterpret_cast<const float4*>(&skL[kk][dg16]);
      float s = 0.0f;
#pragma unroll
      for (int j = 0; j < 4; ++j) {
        const float4 kv = kr[j];
        s += q4[j].x * kv.x + q4[j].y * kv.y + q4[j].z * kv.z + q4[j].w * kv.w;
      }
      s += __shfl_xor(s, 1);
      s += __shfl_xor(s, 2);
      s *= 0.125f;                        // 1/sqrt(64)
      if (s > m + 8.0f) {                 // deferred-max rescale (rare)
        const float c = __expf(m - s);
        m = s; l *= c;
#pragma unroll
        for (int j = 0; j < 4; ++j) {
          acc[j].x *= c; acc[j].y *= c; acc[j].z *= c; acc[j].w *= c;
        }
      }
      const float p = __expf(s - m);
      l += p;
      const float4* vr = reinterpret_cast<const float4*>(&vpL[kk][dg16]);
#pragma unroll
      for (int j = 0; j < 4; ++j) {
        const float4 vv = vr[j];
        acc[j].x += p * vv.x; acc[j].y += p * vv.y;
        acc[j].z += p * vv.z; acc[j].w += p * vv.w;
      }
    }
  }

  float4* o4 = reinterpret_cast<float4*>(orow);
  if (valid) {
    const float invl = 1.0f / l;
#pragma unroll
    for (int j = 0; j < 4; ++j) {
      float4 o;
      o.x = acc[j].x * invl; o.y = acc[j].y * invl;
      o.z = acc[j].z * invl; o.w = acc[j].w * invl;
      o4[j] = o;
    }
  } else {
    const float4 z = {0.f, 0.f, 0.f, 0.f};
    o4[0] = z; o4[1] = z; o4[2] = z; o4[3] = z;
  }
}

// ---------------------------------------------------------------------------
// diff stage 1: per-block partial sums of |io - prev| (deterministic; no atomics)
// ---------------------------------------------------------------------------
__global__ __launch_bounds__(256) void diff_kernel(
    const float* __restrict__ io, const float* __restrict__ prev,
    float* __restrict__ partials, const FState* __restrict__ st, int is_first)
{
  if (st->done) return;   // partials stale but unused when done
  const int tid = threadIdx.x;
  const int gid = blockIdx.x * 256 + tid;
  float s = 0.0f;
  const float4* a = reinterpret_cast<const float4*>(io);
  const float4* b = reinterpret_cast<const float4*>(prev);
  for (int i = gid; i < NHE4; i += DIFF_BLOCKS * 256) {
    float4 v = a[i];
    if (!is_first) {
      const float4 p = b[i];
      v.x -= p.x; v.y -= p.y; v.z -= p.z; v.w -= p.w;
    }
    s += fabsf(v.x) + fabsf(v.y) + fabsf(v.z) + fabsf(v.w);
  }
#pragma unroll
  for (int off = 1; off < 64; off <<= 1) s += __shfl_xor(s, off);
  __shared__ float wsum[4];
  const int lane = tid & 63, wv = tid >> 6;
  if (lane == 0) wsum[wv] = s;
  __syncthreads();
  if (tid == 0) partials[blockIdx.x] = wsum[0] + wsum[1] + wsum[2] + wsum[3];
}

// ---------------------------------------------------------------------------
// diff stage 2 + scalar state update (mirrors reference scan-step logic)
// ---------------------------------------------------------------------------
__global__ __launch_bounds__(256) void state_update_kernel(
    FState* __restrict__ st, const float* __restrict__ partials, int iter)
{
  const int tid = threadIdx.x;
  float s = 0.0f;
  for (int i = tid; i < DIFF_BLOCKS; i += 256) s += partials[i];
  __shared__ float red[256];
  red[tid] = s;
  __syncthreads();
  for (int off = 128; off > 0; off >>= 1) {
    if (tid < off) red[tid] += red[tid + off];
    __syncthreads();
  }
  if (tid == 0) {
    const int done_prev = st->done;
    st->done_prev = done_prev;
    if (!done_prev) {
      const float diff = red[0] * (1.0f / (float)NHE);
      const bool conv = (diff < st->thr + st->fac * diff) && (iter > 0);
      st->upd  = conv ? 0 : 1;
      st->done = conv ? 1 : 0;
      if (!conv) {
        const int cw = st->cw;
        const int up = (int)((float)cw * 1.1f);
        const int dn = (int)((float)cw * 0.9f);
        int nw = (diff > 0.05f) ? up : ((diff < 0.001f && cw > 64) ? dn : cw);
        nw = nw < 64 ? 64 : (nw > TDIM ? TDIM : nw);
        st->cw = nw;
        st->temp += 0.005f;
      }
    } else {
      st->upd = 0;
    }
  }
}

// ---------------------------------------------------------------------------
// carry update: attn = done_prev ? attn : io;  if(upd){ prev=io; qcur+=io; }
// ---------------------------------------------------------------------------
__global__ __launch_bounds__(256) void update_kernel(
    const float* __restrict__ io, float* __restrict__ attn, float* __restrict__ prev,
    float* __restrict__ qcur, const FState* __restrict__ st, int last)
{
  if (st->done_prev) return;   // when done_prev, upd==0 too: nothing to do
  const int upd = st->upd;
  const int i = blockIdx.x * 256 + threadIdx.x;
  if (i >= NHE4) return;
  const float4 v = reinterpret_cast<const float4*>(io)[i];
  reinterpret_cast<float4*>(attn)[i] = v;
  if (!last && upd) {
    reinterpret_cast<float4*>(prev)[i] = v;
    float4 qv = reinterpret_cast<float4*>(qcur)[i];
    qv.x += v.x; qv.y += v.y; qv.z += v.z; qv.w += v.w;
    reinterpret_cast<float4*>(qcur)[i] = qv;
  }
}

// ---------------------------------------------------------------------------
// launch
// ---------------------------------------------------------------------------
extern "C" void kernel_launch(void* const* d_in, const int* in_sizes, int n_in,
                              void* d_out, int out_size, void* d_ws, size_t ws_size,
                              hipStream_t stream)
{
  const float* x   = (const float*)d_in[0];
  const float* Wq  = (const float*)d_in[1];
  const float* bq  = (const float*)d_in[2];
  const float* Wk  = (const float*)d_in[3];
  const float* Wv  = (const float*)d_in[4];
  const float* bv  = (const float*)d_in[5];
  const float* Wo  = (const float*)d_in[6];
  const float* bo  = (const float*)d_in[7];
  const float* lna = (const float*)d_in[8];
  const float* lnb = (const float*)d_in[9];
  const float* lnc = (const float*)d_in[10];
  const float* lnd = (const float*)d_in[11];
  const float* lqw = (const float*)d_in[12];
  const float* lqb = (const float*)d_in[13];
  const float* lkw = (const float*)d_in[14];
  const float* lkb = (const float*)d_in[15];
  const float* lvw = (const float*)d_in[16];
  const float* lvb = (const float*)d_in[17];
  const float* thr = (const float*)d_in[18];
  const float* tb  = (const float*)d_in[19];
  const float* fac = (const float*)d_in[20];
  float* out = (float*)d_out;

  // workspace layout (floats): ~76 MB total
  float* ws   = (float*)d_ws;
  float* xa   = ws;                 // LN(x, lna)
  float* xb   = xa + NHE;           // LN(x, lnb)
  float* qcur = xb + NHE;           // q heads (scaled), then running qcur
  float* skb  = qcur + NHE;         // k heads -> sk (in-place proj)
  float* vpb  = skb + NHE;          // v heads -> vp (in-place proj)
  float* sqb  = vpb + NHE;          // per-iter sq
  float* io   = sqb + NHE;          // iter_out
  float* prev = io + NHE;
  float* attn = prev + NHE;
  float* partials = attn + NHE;
  FState* st = (FState*)(partials + DIFF_BLOCKS);

  constexpr float SC = 0.35355339059327379f;  // 64^-0.25

  hipLaunchKernelGGL(init_kernel, dim3(1), dim3(64), 0, stream, st, thr, tb, fac);
  hipLaunchKernelGGL(ln_x_kernel, dim3(RROWS), dim3(256), 0, stream, x, lna, lnb, xa, xb);

  hipLaunchKernelGGL((gemm_bt_kernel<0, 1, true>),  dim3(32, 16), dim3(256), 0, stream,
                     xa, Wq, bq, qcur, SC);
  hipLaunchKernelGGL((gemm_bt_kernel<0, 1, false>), dim3(32, 16), dim3(256), 0, stream,
                     xb, Wk, (const float*)nullptr, skb, SC);
  hipLaunchKernelGGL((gemm_bt_kernel<0, 1, true>),  dim3(32, 16), dim3(256), 0, stream,
                     xb, Wv, bv, vpb, 1.0f);

  // iteration-invariant: sk = LN(k@lk^T+lk_b, lnd);  vp = v@lv^T+lv_b
  hipLaunchKernelGGL((headproj_kernel<true, false>),  dim3(1024), dim3(256), 0, stream,
                     skb, skb, lkw, lkb, lnd, (const FState*)nullptr);
  hipLaunchKernelGGL((headproj_kernel<false, false>), dim3(1024), dim3(256), 0, stream,
                     vpb, vpb, lvw, lvb, (const float*)nullptr, (const FState*)nullptr);

  for (int it = 0; it < 3; ++it) {
    hipLaunchKernelGGL((headproj_kernel<true, true>), dim3(1024), dim3(256), 0, stream,
                       qcur, sqb, lqw, lqb, lnc, st);
    hipLaunchKernelGGL(attn_kernel, dim3(16, BH), dim3(256), 0, stream,
                       sqb, skb, vpb, io, st);
    hipLaunchKernelGGL(diff_kernel, dim3(DIFF_BLOCKS), dim3(256), 0, stream,
                       io, prev, partials, st, it == 0 ? 1 : 0);
    hipLaunchKernelGGL(state_update_kernel, dim3(1), dim3(256), 0, stream,
                       st, partials, it);
    hipLaunchKernelGGL(update_kernel, dim3(NHE4 / 256), dim3(256), 0, stream,
                       io, attn, prev, qcur, st, it == 2 ? 1 : 0);
  }

  hipLaunchKernelGGL((gemm_bt_kernel<1, 0, true>), dim3(32, 16), dim3(256), 0, stream,
                     attn, Wo, bo, out, 1.0f);
}

// Round 2
// 684.790 us; speedup vs baseline: 1.7210x; 1.7210x over previous
//
#include <hip/hip_runtime.h>
#include <hip/hip_bf16.h>

// Sizes (fixed by the reference)
#define BDIM 2
#define TDIM 1024
#define DDIM 1024
#define HDIM 16
#define HD   64
#define RROWS (BDIM * TDIM)        // 2048 rows for the big GEMMs
#define BH    (BDIM * HDIM)        // 32 (b,h) pairs
#define NHE   (BH * TDIM * HD)     // 2,097,152 elements in head layout
#define NHE4  (NHE / 4)
#define DIFF_BLOCKS 1024
#define L2E 1.4426950408889634f

typedef __attribute__((ext_vector_type(8))) short short8v;
typedef __attribute__((ext_vector_type(4))) float f32x4;

struct FState {
  int   cw;
  float temp;
  int   done;
  int   upd;
  int   done_prev;
  float thr;
  float fac;
  int   pad;
};

static __device__ __forceinline__ unsigned short f2bf(float x) {
  __hip_bfloat16 h = __float2bfloat16(x);
  return __builtin_bit_cast(unsigned short, h);
}

// ---------------------------------------------------------------------------
__global__ void init_kernel(FState* st, const float* thr, const float* tb, const float* fac) {
  if (threadIdx.x == 0 && blockIdx.x == 0) {
    st->cw = TDIM;                        // max(min(1024,2048),64)
    st->temp = tb[0];
    st->done = 0;
    st->done_prev = 0;
    st->upd = 1;
    st->thr = thr[0];
    st->fac = fac[0];
  }
}

// ---------------------------------------------------------------------------
// LayerNorm of x with two weight vectors (shared mean/var)
// ---------------------------------------------------------------------------
__global__ __launch_bounds__(256) void ln_x_kernel(
    const float* __restrict__ x, const float* __restrict__ wa, const float* __restrict__ wb,
    float* __restrict__ xa, float* __restrict__ xb)
{
  const int row = blockIdx.x;
  const int tid = threadIdx.x;
  const float4 v = reinterpret_cast<const float4*>(x + (size_t)row * DDIM)[tid];
  float s = v.x + v.y + v.z + v.w;
  float q = v.x * v.x + v.y * v.y + v.z * v.z + v.w * v.w;
#pragma unroll
  for (int off = 1; off < 64; off <<= 1) {
    s += __shfl_xor(s, off);
    q += __shfl_xor(q, off);
  }
  __shared__ float ss[4], qq[4];
  const int lane = tid & 63, wv = tid >> 6;
  if (lane == 0) { ss[wv] = s; qq[wv] = q; }
  __syncthreads();
  s = ss[0] + ss[1] + ss[2] + ss[3];
  q = qq[0] + qq[1] + qq[2] + qq[3];
  const float mean = s * (1.0f / DDIM);
  const float var  = q * (1.0f / DDIM) - mean * mean;
  const float inv  = rsqrtf(var + 1e-5f);
  const float4 a4 = reinterpret_cast<const float4*>(wa)[tid];
  const float4 b4 = reinterpret_cast<const float4*>(wb)[tid];
  float4 h;
  h.x = (v.x - mean) * inv; h.y = (v.y - mean) * inv;
  h.z = (v.z - mean) * inv; h.w = (v.w - mean) * inv;
  float4 oa, ob;
  oa.x = h.x * a4.x; oa.y = h.y * a4.y; oa.z = h.z * a4.z; oa.w = h.w * a4.w;
  ob.x = h.x * b4.x; ob.y = h.y * b4.y; ob.z = h.z * b4.z; ob.w = h.w * b4.w;
  reinterpret_cast<float4*>(xa + (size_t)row * DDIM)[tid] = oa;
  reinterpret_cast<float4*>(xb + (size_t)row * DDIM)[tid] = ob;
}

// ---------------------------------------------------------------------------
// fp32 tiled GEMM: C = (A @ W^T + bias) * scale   (unchanged from round 1)
// ---------------------------------------------------------------------------
template<int AMODE, int CMODE, bool HASBIAS>
__global__ __launch_bounds__(256) void gemm_bt_kernel(
    const float* __restrict__ A, const float* __restrict__ W,
    const float* __restrict__ bias, float* __restrict__ C, float scale)
{
  __shared__ __align__(16) float As[16][64];
  __shared__ __align__(16) float Ws[16][64];
  const int tid = threadIdx.x;
  const int bm = blockIdx.x;
  const int bn = blockIdx.y;
  const int ty = tid >> 4, tx = tid & 15;
  float acc[4][4] = {};
  for (int kt = 0; kt < DDIM; kt += 16) {
    __syncthreads();
#pragma unroll
    for (int j = 0; j < 4; ++j) {
      const int idx = tid + j * 256;
      const int kk = idx & 15, mm = idx >> 4;
      const int k = kt + kk;
      const int r = bm * 64 + mm;
      size_t ai;
      if (AMODE == 0) {
        ai = (size_t)r * DDIM + k;
      } else {
        const int b = r >> 10, t = r & (TDIM - 1);
        ai = ((size_t)(b * HDIM + (k >> 6)) * TDIM + t) * HD + (k & 63);
      }
      As[kk][mm] = A[ai];
      const int n = bn * 64 + mm;
      Ws[kk][mm] = W[(size_t)n * DDIM + k];
    }
    __syncthreads();
#pragma unroll
    for (int kk = 0; kk < 16; ++kk) {
      const float4 a = *reinterpret_cast<const float4*>(&As[kk][ty * 4]);
      const float4 w = *reinterpret_cast<const float4*>(&Ws[kk][tx * 4]);
      const float av[4] = {a.x, a.y, a.z, a.w};
      const float wv[4] = {w.x, w.y, w.z, w.w};
#pragma unroll
      for (int i = 0; i < 4; ++i)
#pragma unroll
        for (int j = 0; j < 4; ++j) acc[i][j] += av[i] * wv[j];
    }
  }
#pragma unroll
  for (int i = 0; i < 4; ++i) {
    const int r = bm * 64 + ty * 4 + i;
    const int b = r >> 10, t = r & (TDIM - 1);
#pragma unroll
    for (int j = 0; j < 4; ++j) {
      const int n = bn * 64 + tx * 4 + j;
      float v = acc[i][j];
      if constexpr (HASBIAS) v += bias[n];
      v *= scale;
      size_t ci;
      if (CMODE == 0) ci = (size_t)r * DDIM + n;
      else ci = ((size_t)(b * HDIM + (n >> 6)) * TDIM + t) * HD + (n & 63);
      C[ci] = v;
    }
  }
}

// ---------------------------------------------------------------------------
// per-head 64x64 projection -> bf16 outputs for the MFMA attention.
// OUT_MODE 0: bf16 [t][hd] row layout (sk, sq). OUT_MODE 1: bf16 transposed
// [hd][t] via LDS tile (vp). IS_SQ: gate on done, skip rows >= cw, fold
// tscale * 1/sqrt(64).
// ---------------------------------------------------------------------------
template<int OUT_MODE, bool DO_LN, bool IS_SQ>
__global__ __launch_bounds__(256) void headproj_kernel(
    const float* __restrict__ in, unsigned short* __restrict__ out,
    const float* __restrict__ w, const float* __restrict__ bias,
    const float* __restrict__ lnw, const FState* __restrict__ st)
{
  if constexpr (IS_SQ) { if (st->done) return; }
  __shared__ float wl[64 * 65];
  __shared__ unsigned short tT[64 * 34];
  const int tid = threadIdx.x;
  for (int idx = tid; idx < 4096; idx += 256) {
    const int d = idx >> 6, i = idx & 63;
    wl[i * 65 + d] = w[idx];
  }
  const int lane = tid & 63, wv = tid >> 6;
  const float bd = bias[lane];
  float lw = 1.0f;
  if constexpr (DO_LN) lw = lnw[lane];
  float ts = 1.0f;
  int cw = TDIM;
  if constexpr (IS_SQ) {
    const float tp = st->temp;
    ts = (tp > 0.0f ? rsqrtf(tp) : 1.0f) * 0.125f;   // fold 1/sqrt(64)
    cw = st->cw;
  }
  __syncthreads();
  const int rowBase = blockIdx.x * 32 + wv * 8;
  for (int rr = 0; rr < 8; ++rr) {
    const int row = rowBase + rr;
    if constexpr (IS_SQ) {
      if ((row & (TDIM - 1)) >= cw) continue;
    }
    const float h = in[(size_t)row * HD + lane];
    float y = bd;
#pragma unroll
    for (int i = 0; i < 64; ++i) {
      const float hv = __uint_as_float((unsigned)__builtin_amdgcn_readlane((int)__float_as_uint(h), i));
      y += wl[i * 65 + lane] * hv;
    }
    if constexpr (DO_LN) {
      float s = y;
#pragma unroll
      for (int off = 1; off < 64; off <<= 1) s += __shfl_xor(s, off);
      const float mean = s * (1.0f / 64.0f);
      const float t0 = y - mean;
      float v2 = t0 * t0;
#pragma unroll
      for (int off = 1; off < 64; off <<= 1) v2 += __shfl_xor(v2, off);
      y = t0 * rsqrtf(v2 * (1.0f / 64.0f) + 1e-5f) * lw;
    }
    if constexpr (IS_SQ) y *= ts;
    if constexpr (OUT_MODE == 0) {
      out[(size_t)row * HD + lane] = f2bf(y);
    } else {
      tT[lane * 34 + wv * 8 + rr] = f2bf(y);
    }
  }
  if constexpr (OUT_MODE == 1) {
    __syncthreads();
    const int hd = tid >> 2, tseg = (tid & 3) * 8;
    const int r0 = blockIdx.x * 32;
    const int bh = r0 >> 10, t0 = r0 & (TDIM - 1);
    short8v v;
#pragma unroll
    for (int i = 0; i < 8; ++i) v[i] = (short)tT[hd * 34 + tseg + i];
    *reinterpret_cast<short8v*>(out + ((size_t)bh * HD + hd) * TDIM + t0 + tseg) = v;
  }
}

// ---------------------------------------------------------------------------
// MFMA flash attention (bf16 inputs, fp32 softmax/accum).
// Block = 4 waves; wave owns 16 q-rows. Swapped QK^T: S^T = mfma(K, Q) so a
// lane holds 16 key-scores for one q-row. P^ routed via per-wave swizzled LDS
// to PV B-frags; PV computes O^T = mfma(V^T, P^). No barriers in the k-loop.
// ---------------------------------------------------------------------------
__global__ __launch_bounds__(256) void attn_mfma_kernel(
    const unsigned short* __restrict__ sq, const unsigned short* __restrict__ sk,
    const unsigned short* __restrict__ vpT, float* __restrict__ io,
    const FState* __restrict__ st)
{
  if (st->done) return;
  const int cw = st->cw;
  const int bh = blockIdx.y;
  const int tid = threadIdx.x;
  const int wv = tid >> 6, lane = tid & 63;
  const int ql = lane & 15, hi = lane >> 4;
  const int qbase = blockIdx.x * 64 + wv * 16;
  const int q = qbase + ql;
  const size_t baseRow = (size_t)bh * TDIM * HD;    // [t][hd] element base
  const size_t baseT   = (size_t)bh * HD * TDIM;    // [hd][t] element base
  float* orow = io + baseRow + (size_t)q * HD;

  if (qbase >= cw) {                // wave fully out of window: zeros
    const f32x4 z = {0.f, 0.f, 0.f, 0.f};
#pragma unroll
    for (int f = 0; f < 4; ++f)
      *reinterpret_cast<f32x4*>(orow + f * 16 + hi * 4) = z;
    return;
  }

  __shared__ __align__(16) unsigned char Plds[4 * 2048];
  unsigned char* P = Plds + wv * 2048;
  const unsigned swz = (unsigned)((ql & 7) << 4);

  short8v qf0, qf1;
  {
    const unsigned short* qp = sq + baseRow + (size_t)q * HD + hi * 8;
    qf0 = *reinterpret_cast<const short8v*>(qp);
    qf1 = *reinterpret_cast<const short8v*>(qp + 32);
  }

  float m = -1e30f, l = 0.f;
  f32x4 o[4] = {};
  const int nch = (cw + 63) >> 6;
  for (int ch = 0; ch < nch; ++ch) {
    const int k0 = ch * 64;
    // ---- QK^T: S^T[key][q], 4 key-frags of 16
    f32x4 s[4];
#pragma unroll
    for (int f = 0; f < 4; ++f) {
      const unsigned short* kp = sk + baseRow + (size_t)(k0 + f * 16 + ql) * HD + hi * 8;
      const short8v a0 = *reinterpret_cast<const short8v*>(kp);
      const short8v a1 = *reinterpret_cast<const short8v*>(kp + 32);
      f32x4 acc = {};
      acc = __builtin_amdgcn_mfma_f32_16x16x32_bf16(a0, qf0, acc, 0, 0, 0);
      acc = __builtin_amdgcn_mfma_f32_16x16x32_bf16(a1, qf1, acc, 0, 0, 0);
      s[f] = acc;
    }
    // ---- mask + chunk max (lane holds keys k0 + f*16 + hi*4 + r for its q)
    float mc = -1e30f;
#pragma unroll
    for (int f = 0; f < 4; ++f) {
#pragma unroll
      for (int r = 0; r < 4; ++r) {
        float v = s[f][r];
        if (k0 + f * 16 + hi * 4 + r >= cw) v = -1e30f;
        s[f][r] = v;
        mc = fmaxf(mc, v);
      }
    }
    mc = fmaxf(mc, __shfl_xor(mc, 16));
    mc = fmaxf(mc, __shfl_xor(mc, 32));
    const float mn = fmaxf(m, mc);
    const float c = __builtin_amdgcn_exp2f((m - mn) * L2E);
    // ---- exp + pack bf16 pairs
    float ls = 0.f;
    unsigned pk[8];
#pragma unroll
    for (int f = 0; f < 4; ++f) {
      const float p0 = __builtin_amdgcn_exp2f((s[f][0] - mn) * L2E);
      const float p1 = __builtin_amdgcn_exp2f((s[f][1] - mn) * L2E);
      const float p2 = __builtin_amdgcn_exp2f((s[f][2] - mn) * L2E);
      const float p3 = __builtin_amdgcn_exp2f((s[f][3] - mn) * L2E);
      ls += (p0 + p1) + (p2 + p3);
      pk[f * 2]     = (unsigned)f2bf(p0) | ((unsigned)f2bf(p1) << 16);
      pk[f * 2 + 1] = (unsigned)f2bf(p2) | ((unsigned)f2bf(p3) << 16);
    }
    ls += __shfl_xor(ls, 16);
    ls += __shfl_xor(ls, 32);
    l = l * c + ls;
    m = mn;
#pragma unroll
    for (int f = 0; f < 4; ++f) o[f] *= c;
    // ---- P^ -> per-wave LDS (swizzled)
    const unsigned wb = (unsigned)(ql * 128 + hi * 8);
#pragma unroll
    for (int f = 0; f < 4; ++f) {
      *reinterpret_cast<unsigned*>(P + ((wb + f * 32)     ^ swz)) = pk[f * 2];
      *reinterpret_cast<unsigned*>(P + ((wb + f * 32 + 4) ^ swz)) = pk[f * 2 + 1];
    }
    // ---- PV: O^T[hd][q] += V^T · P^
#pragma unroll
    for (int kh = 0; kh < 2; ++kh) {
      const short8v pb = *reinterpret_cast<short8v*>(
          P + ((unsigned)(ql * 128 + kh * 64 + hi * 16) ^ swz));
#pragma unroll
      for (int f = 0; f < 4; ++f) {
        const unsigned short* vp = vpT + baseT + (size_t)(f * 16 + ql) * TDIM + k0 + kh * 32 + hi * 8;
        const short8v av = *reinterpret_cast<const short8v*>(vp);
        o[f] = __builtin_amdgcn_mfma_f32_16x16x32_bf16(av, pb, o[f], 0, 0, 0);
      }
    }
  }
  // ---- epilogue: divide by l, zero invalid q rows, coalesced f32x4 stores
  const bool valid = (q < cw);
  const float invl = valid ? (1.0f / l) : 0.0f;
#pragma unroll
  for (int f = 0; f < 4; ++f) {
    f32x4 vo = o[f] * invl;
    *reinterpret_cast<f32x4*>(orow + f * 16 + hi * 4) = vo;
  }
}

// ---------------------------------------------------------------------------
// diff stage 1 (deterministic partial sums)
// ---------------------------------------------------------------------------
__global__ __launch_bounds__(256) void diff_kernel(
    const float* __restrict__ io, const float* __restrict__ prev,
    float* __restrict__ partials, const FState* __restrict__ st, int is_first)
{
  if (st->done) return;
  const int tid = threadIdx.x;
  const int gid = blockIdx.x * 256 + tid;
  float s = 0.0f;
  const float4* a = reinterpret_cast<const float4*>(io);
  const float4* b = reinterpret_cast<const float4*>(prev);
  for (int i = gid; i < NHE4; i += DIFF_BLOCKS * 256) {
    float4 v = a[i];
    if (!is_first) {
      const float4 p = b[i];
      v.x -= p.x; v.y -= p.y; v.z -= p.z; v.w -= p.w;
    }
    s += fabsf(v.x) + fabsf(v.y) + fabsf(v.z) + fabsf(v.w);
  }
#pragma unroll
  for (int off = 1; off < 64; off <<= 1) s += __shfl_xor(s, off);
  __shared__ float wsum[4];
  const int lane = tid & 63, wv = tid >> 6;
  if (lane == 0) wsum[wv] = s;
  __syncthreads();
  if (tid == 0) partials[blockIdx.x] = wsum[0] + wsum[1] + wsum[2] + wsum[3];
}

// ---------------------------------------------------------------------------
__global__ __launch_bounds__(256) void state_update_kernel(
    FState* __restrict__ st, const float* __restrict__ partials, int iter)
{
  const int tid = threadIdx.x;
  float s = 0.0f;
  for (int i = tid; i < DIFF_BLOCKS; i += 256) s += partials[i];
  __shared__ float red[256];
  red[tid] = s;
  __syncthreads();
  for (int off = 128; off > 0; off >>= 1) {
    if (tid < off) red[tid] += red[tid + off];
    __syncthreads();
  }
  if (tid == 0) {
    const int done_prev = st->done;
    st->done_prev = done_prev;
    if (!done_prev) {
      const float diff = red[0] * (1.0f / (float)NHE);
      const bool conv = (diff < st->thr + st->fac * diff) && (iter > 0);
      st->upd  = conv ? 0 : 1;
      st->done = conv ? 1 : 0;
      if (!conv) {
        const int cw = st->cw;
        const int up = (int)((float)cw * 1.1f);
        const int dn = (int)((float)cw * 0.9f);
        int nw = (diff > 0.05f) ? up : ((diff < 0.001f && cw > 64) ? dn : cw);
        nw = nw < 64 ? 64 : (nw > TDIM ? TDIM : nw);
        st->cw = nw;
        st->temp += 0.005f;
      }
    } else {
      st->upd = 0;
    }
  }
}

// ---------------------------------------------------------------------------
__global__ __launch_bounds__(256) void update_kernel(
    const float* __restrict__ io, float* __restrict__ attn, float* __restrict__ prev,
    float* __restrict__ qcur, const FState* __restrict__ st, int last)
{
  if (st->done_prev) return;
  const int upd = st->upd;
  const int i = blockIdx.x * 256 + threadIdx.x;
  if (i >= NHE4) return;
  const float4 v = reinterpret_cast<const float4*>(io)[i];
  reinterpret_cast<float4*>(attn)[i] = v;
  if (!last && upd) {
    reinterpret_cast<float4*>(prev)[i] = v;
    float4 qv = reinterpret_cast<float4*>(qcur)[i];
    qv.x += v.x; qv.y += v.y; qv.z += v.z; qv.w += v.w;
    reinterpret_cast<float4*>(qcur)[i] = qv;
  }
}

// ---------------------------------------------------------------------------
extern "C" void kernel_launch(void* const* d_in, const int* in_sizes, int n_in,
                              void* d_out, int out_size, void* d_ws, size_t ws_size,
                              hipStream_t stream)
{
  const float* x   = (const float*)d_in[0];
  const float* Wq  = (const float*)d_in[1];
  const float* bq  = (const float*)d_in[2];
  const float* Wk  = (const float*)d_in[3];
  const float* Wv  = (const float*)d_in[4];
  const float* bv  = (const float*)d_in[5];
  const float* Wo  = (const float*)d_in[6];
  const float* bo  = (const float*)d_in[7];
  const float* lna = (const float*)d_in[8];
  const float* lnb = (const float*)d_in[9];
  const float* lnc = (const float*)d_in[10];
  const float* lnd = (const float*)d_in[11];
  const float* lqw = (const float*)d_in[12];
  const float* lqb = (const float*)d_in[13];
  const float* lkw = (const float*)d_in[14];
  const float* lkb = (const float*)d_in[15];
  const float* lvw = (const float*)d_in[16];
  const float* lvb = (const float*)d_in[17];
  const float* thr = (const float*)d_in[18];
  const float* tb  = (const float*)d_in[19];
  const float* fac = (const float*)d_in[20];
  float* out = (float*)d_out;

  // workspace layout: 5 aliased f32 buffers (8MB each) + bf16 buffers (12MB)
  float* f0   = (float*)d_ws;
  float* xa   = f0;                 // aliases io (attn writes after last xa read)
  float* io   = f0;
  float* xb   = f0 + (size_t)NHE;       // aliases prev
  float* prev = xb;
  float* qcur = f0 + 2 * (size_t)NHE;
  float* ktmp = f0 + 3 * (size_t)NHE;   // aliases attn
  float* attn = ktmp;
  float* vtmp = f0 + 4 * (size_t)NHE;
  float* partials = f0 + 5 * (size_t)NHE;
  FState* st = (FState*)(partials + DIFF_BLOCKS);
  unsigned short* u0  = (unsigned short*)(partials + DIFF_BLOCKS + 16);
  unsigned short* sqb = u0;                      // bf16 [bh][t][hd]
  unsigned short* skb = u0 + (size_t)NHE;        // bf16 [bh][t][hd]
  unsigned short* vpT = u0 + 2 * (size_t)NHE;    // bf16 [bh][hd][t]

  constexpr float SC = 0.35355339059327379f;  // 64^-0.25

  hipLaunchKernelGGL(init_kernel, dim3(1), dim3(64), 0, stream, st, thr, tb, fac);
  hipLaunchKernelGGL(ln_x_kernel, dim3(RROWS), dim3(256), 0, stream, x, lna, lnb, xa, xb);

  hipLaunchKernelGGL((gemm_bt_kernel<0, 1, true>),  dim3(32, 16), dim3(256), 0, stream,
                     xa, Wq, bq, qcur, SC);
  hipLaunchKernelGGL((gemm_bt_kernel<0, 1, false>), dim3(32, 16), dim3(256), 0, stream,
                     xb, Wk, (const float*)nullptr, ktmp, SC);
  hipLaunchKernelGGL((gemm_bt_kernel<0, 1, true>),  dim3(32, 16), dim3(256), 0, stream,
                     xb, Wv, bv, vtmp, 1.0f);

  // iteration-invariant: sk = LN(k@lk^T+lk_b, lnd) -> bf16; vp -> bf16 transposed
  hipLaunchKernelGGL((headproj_kernel<0, true, false>), dim3(1024), dim3(256), 0, stream,
                     ktmp, skb, lkw, lkb, lnd, (const FState*)nullptr);
  hipLaunchKernelGGL((headproj_kernel<1, false, false>), dim3(1024), dim3(256), 0, stream,
                     vtmp, vpT, lvw, lvb, (const float*)nullptr, (const FState*)nullptr);

  for (int it = 0; it < 3; ++it) {
    hipLaunchKernelGGL((headproj_kernel<0, true, true>), dim3(1024), dim3(256), 0, stream,
                       qcur, sqb, lqw, lqb, lnc, st);
    hipLaunchKernelGGL(attn_mfma_kernel, dim3(16, BH), dim3(256), 0, stream,
                       sqb, skb, vpT, io, st);
    hipLaunchKernelGGL(diff_kernel, dim3(DIFF_BLOCKS), dim3(256), 0, stream,
                       io, prev, partials, st, it == 0 ? 1 : 0);
    hipLaunchKernelGGL(state_update_kernel, dim3(1), dim3(256), 0, stream,
                       st, partials, it);
    hipLaunchKernelGGL(update_kernel, dim3(NHE4 / 256), dim3(256), 0, stream,
                       io, attn, prev, qcur, st, it == 2 ? 1 : 0);
  }

  hipLaunchKernelGGL((gemm_bt_kernel<1, 0, true>), dim3(32, 16), dim3(256), 0, stream,
                     attn, Wo, bo, out, 1.0f);
}

// Round 3
// 370.378 us; speedup vs baseline: 3.1819x; 1.8489x over previous
//
#include <hip/hip_runtime.h>
#include <hip/hip_bf16.h>

// Sizes (fixed by the reference)
#define BDIM 2
#define TDIM 1024
#define DDIM 1024
#define HDIM 16
#define HD   64
#define RROWS (BDIM * TDIM)        // 2048 rows for the big GEMMs
#define BH    (BDIM * HDIM)        // 32 (b,h) pairs
#define NHE   (BH * TDIM * HD)     // 2,097,152 elements in head layout
#define NHE4  (NHE / 4)
#define DIFF_BLOCKS 1024
#define L2E 1.4426950408889634f

typedef __attribute__((ext_vector_type(8))) short short8v;
typedef __attribute__((ext_vector_type(4))) short short4v;
typedef __attribute__((ext_vector_type(4))) float f32x4;

struct FState {
  int   cw;
  float temp;
  int   done;
  int   upd;
  int   done_prev;
  float thr;
  float fac;
  int   pad;
};

static __device__ __forceinline__ unsigned short f2bf(float x) {
  __hip_bfloat16 h = __float2bfloat16(x);
  return __builtin_bit_cast(unsigned short, h);
}
static __device__ __forceinline__ float bf2f(unsigned short u) {
  unsigned v = ((unsigned)u) << 16;
  return __builtin_bit_cast(float, v);
}
// async global->LDS, 16B per lane. LDS dest is wave-uniform base (+lane*16 by HW).
static __device__ __forceinline__ void gload16(const void* g, void* l) {
  __builtin_amdgcn_global_load_lds(
      (const __attribute__((address_space(1))) void*)g,
      (__attribute__((address_space(3))) void*)l, 16, 0, 0);
}

// ---------------------------------------------------------------------------
__global__ void init_kernel(FState* st, const float* thr, const float* tb, const float* fac) {
  if (threadIdx.x == 0 && blockIdx.x == 0) {
    st->cw = TDIM;
    st->temp = tb[0];
    st->done = 0;
    st->done_prev = 0;
    st->upd = 1;
    st->thr = thr[0];
    st->fac = fac[0];
  }
}

// ---------------------------------------------------------------------------
// LayerNorm of x with two weight vectors (shared mean/var) -> split-bf16
// planes [2048][2048]: cols [0,1024) = hi, [1024,2048) = lo.
// ---------------------------------------------------------------------------
__global__ __launch_bounds__(256) void ln_x_kernel(
    const float* __restrict__ x, const float* __restrict__ wa, const float* __restrict__ wb,
    unsigned short* __restrict__ xaS, unsigned short* __restrict__ xbS)
{
  const int row = blockIdx.x;
  const int tid = threadIdx.x;
  const float4 v = reinterpret_cast<const float4*>(x + (size_t)row * DDIM)[tid];
  float s = v.x + v.y + v.z + v.w;
  float q = v.x * v.x + v.y * v.y + v.z * v.z + v.w * v.w;
#pragma unroll
  for (int off = 1; off < 64; off <<= 1) {
    s += __shfl_xor(s, off);
    q += __shfl_xor(q, off);
  }
  __shared__ float ss[4], qq[4];
  const int lane = tid & 63, wv = tid >> 6;
  if (lane == 0) { ss[wv] = s; qq[wv] = q; }
  __syncthreads();
  s = ss[0] + ss[1] + ss[2] + ss[3];
  q = qq[0] + qq[1] + qq[2] + qq[3];
  const float mean = s * (1.0f / DDIM);
  const float var  = q * (1.0f / DDIM) - mean * mean;
  const float inv  = rsqrtf(var + 1e-5f);
  const float4 a4 = reinterpret_cast<const float4*>(wa)[tid];
  const float4 b4 = reinterpret_cast<const float4*>(wb)[tid];
  const float hv[4] = { (v.x - mean) * inv, (v.y - mean) * inv,
                        (v.z - mean) * inv, (v.w - mean) * inv };
  const float av[4] = { a4.x, a4.y, a4.z, a4.w };
  const float bv[4] = { b4.x, b4.y, b4.z, b4.w };
  short4v ah, al, bh, bl;
#pragma unroll
  for (int j = 0; j < 4; ++j) {
    const float oa = hv[j] * av[j];
    const float ob = hv[j] * bv[j];
    const unsigned short oah = f2bf(oa);
    const unsigned short obh = f2bf(ob);
    ah[j] = (short)oah; al[j] = (short)f2bf(oa - bf2f(oah));
    bh[j] = (short)obh; bl[j] = (short)f2bf(ob - bf2f(obh));
  }
  unsigned short* pa = xaS + (size_t)row * 2048 + tid * 4;
  unsigned short* pb = xbS + (size_t)row * 2048 + tid * 4;
  *reinterpret_cast<short4v*>(pa) = ah;
  *reinterpret_cast<short4v*>(pa + 1024) = al;
  *reinterpret_cast<short4v*>(pb) = bh;
  *reinterpret_cast<short4v*>(pb + 1024) = bl;
}

// ---------------------------------------------------------------------------
// split the 4 weight matrices [1024][1024] f32 -> [1024][2048] bf16 (hi|lo)
// ---------------------------------------------------------------------------
__global__ __launch_bounds__(256) void w_split_kernel(
    const float* __restrict__ W0, const float* __restrict__ W1,
    const float* __restrict__ W2, const float* __restrict__ W3,
    unsigned short* __restrict__ O0, unsigned short* __restrict__ O1,
    unsigned short* __restrict__ O2, unsigned short* __restrict__ O3)
{
  const float* W; unsigned short* O;
  switch (blockIdx.y) {
    case 0:  W = W0; O = O0; break;
    case 1:  W = W1; O = O1; break;
    case 2:  W = W2; O = O2; break;
    default: W = W3; O = O3; break;
  }
  const int r = blockIdx.x;
  const int tid = threadIdx.x;
  const float4 v = reinterpret_cast<const float4*>(W + (size_t)r * 1024)[tid];
  const float vv[4] = { v.x, v.y, v.z, v.w };
  short4v h, l;
#pragma unroll
  for (int j = 0; j < 4; ++j) {
    const unsigned short hb = f2bf(vv[j]);
    h[j] = (short)hb;
    l[j] = (short)f2bf(vv[j] - bf2f(hb));
  }
  unsigned short* p = O + (size_t)r * 2048 + tid * 4;
  *reinterpret_cast<short4v*>(p) = h;
  *reinterpret_cast<short4v*>(p + 1024) = l;
}

// ---------------------------------------------------------------------------
// Split-bf16 MFMA GEMM: C = (A @ W^T + bias) * scale with fp32-equivalent
// accuracy via 3 K-segments: A_hi*W_hi + A_lo*W_hi + A_hi*W_lo (logical K=3072).
// A planes [2048][2048] bf16 (hi|lo); W planes [1024][2048] bf16 (hi|lo).
// 128x128 tile, BK=32, 4 waves (2x2), 4x4 16x16x32 frags per wave.
// Staging via global_load_lds dwordx4, linear LDS, 2-barrier loop (m97 recipe).
// CMODE 0: C row-major f32. CMODE 1: C scattered to head layout [B,H,T,64] f32.
// blockIdx.z selects one of up to 3 fused GEMMs.
// ---------------------------------------------------------------------------
template<int CMODE>
__global__ __launch_bounds__(256) void gemm_mfma_kernel(
    const unsigned short* __restrict__ A0, const unsigned short* __restrict__ W0,
    const float* __restrict__ b0, float* __restrict__ C0, float s0,
    const unsigned short* __restrict__ A1, const unsigned short* __restrict__ W1,
    const float* __restrict__ b1, float* __restrict__ C1, float s1,
    const unsigned short* __restrict__ A2, const unsigned short* __restrict__ W2,
    const float* __restrict__ b2, float* __restrict__ C2, float s2)
{
  const unsigned short* A; const unsigned short* W; const float* bias; float* C; float scale;
  switch (blockIdx.z) {
    case 0:  A = A0; W = W0; bias = b0; C = C0; scale = s0; break;
    case 1:  A = A1; W = W1; bias = b1; C = C1; scale = s1; break;
    default: A = A2; W = W2; bias = b2; C = C2; scale = s2; break;
  }
  __shared__ __align__(16) unsigned short As[128 * 32];
  __shared__ __align__(16) unsigned short Ws[128 * 32];
  const int tid = threadIdx.x;
  const int wv = tid >> 6, lane = tid & 63;
  const int wm = wv >> 1, wn = wv & 1;
  const int bm = blockIdx.x;           // M blocks (2048/128 = 16)
  const int bn = blockIdx.y;           // N blocks (1024/128 = 8)

  // staging: wave wv covers chunks j=0,1 of 16 rows each; lane i -> row i>>2,
  // 16B col (i&3)*16 within a 64B k-row. LDS dest is linear row-major.
  const unsigned short* gA[2]; const unsigned short* gW[2];
  unsigned short* lA[2]; unsigned short* lW[2];
#pragma unroll
  for (int j = 0; j < 2; ++j) {
    const int chunk = wv * 2 + j;                  // 0..7
    const int r = chunk * 16 + (lane >> 2);
    const int ce = (lane & 3) * 8;                 // element col within 32
    gA[j] = A + (size_t)(bm * 128 + r) * 2048 + ce;
    gW[j] = W + (size_t)(bn * 128 + r) * 2048 + ce;
    lA[j] = As + chunk * 512;                      // wave-uniform base
    lW[j] = Ws + chunk * 512;
  }

  f32x4 acc[4][4] = {};
  const int rb = lane & 15;
  const int kb = (lane >> 4) * 8;

  for (int seg = 0; seg < 3; ++seg) {
    const int aoff = (seg == 1) ? 1024 : 0;   // A: hi, lo, hi
    const int woff = (seg == 2) ? 1024 : 0;   // W: hi, hi, lo
    for (int ks = 0; ks < 1024; ks += 32) {
      __syncthreads();
#pragma unroll
      for (int j = 0; j < 2; ++j) {
        gload16(gA[j] + aoff + ks, lA[j]);
        gload16(gW[j] + woff + ks, lW[j]);
      }
      __syncthreads();
      short8v af[4], wf[4];
#pragma unroll
      for (int f = 0; f < 4; ++f) {
        af[f] = *reinterpret_cast<const short8v*>(As + (wm * 64 + f * 16 + rb) * 32 + kb);
        wf[f] = *reinterpret_cast<const short8v*>(Ws + (wn * 64 + f * 16 + rb) * 32 + kb);
      }
#pragma unroll
      for (int i = 0; i < 4; ++i)
#pragma unroll
        for (int j2 = 0; j2 < 4; ++j2)
          acc[i][j2] = __builtin_amdgcn_mfma_f32_16x16x32_bf16(af[i], wf[j2], acc[i][j2], 0, 0, 0);
    }
  }

  // epilogue: D col = lane&15 -> n, row = (lane>>4)*4 + r -> m
#pragma unroll
  for (int j2 = 0; j2 < 4; ++j2) {
    const int n = bn * 128 + wn * 64 + j2 * 16 + (lane & 15);
    const float bv_ = bias ? bias[n] : 0.0f;
#pragma unroll
    for (int i = 0; i < 4; ++i) {
#pragma unroll
      for (int r = 0; r < 4; ++r) {
        const int m = bm * 128 + wm * 64 + i * 16 + (lane >> 4) * 4 + r;
        const float v = (acc[i][j2][r] + bv_) * scale;
        size_t ci;
        if constexpr (CMODE == 0) {
          ci = (size_t)m * 1024 + n;
        } else {
          const int b = m >> 10, t = m & (TDIM - 1);
          ci = ((size_t)(b * HDIM + (n >> 6)) * TDIM + t) * HD + (n & 63);
        }
        C[ci] = v;
      }
    }
  }
}

// ---------------------------------------------------------------------------
// per-head 64x64 projection -> bf16 outputs for the MFMA attention.
// OUT_MODE 0: bf16 [t][hd]. OUT_MODE 1: bf16 transposed [hd][t]. IS_SQ: gate
// on done, skip rows >= cw, fold tscale * 1/sqrt(64).
// ---------------------------------------------------------------------------
template<int OUT_MODE, bool DO_LN, bool IS_SQ>
__global__ __launch_bounds__(256) void headproj_kernel(
    const float* __restrict__ in, unsigned short* __restrict__ out,
    const float* __restrict__ w, const float* __restrict__ bias,
    const float* __restrict__ lnw, const FState* __restrict__ st)
{
  if constexpr (IS_SQ) { if (st->done) return; }
  __shared__ float wl[64 * 65];
  __shared__ unsigned short tT[64 * 34];
  const int tid = threadIdx.x;
  for (int idx = tid; idx < 4096; idx += 256) {
    const int d = idx >> 6, i = idx & 63;
    wl[i * 65 + d] = w[idx];
  }
  const int lane = tid & 63, wv = tid >> 6;
  const float bd = bias[lane];
  float lw = 1.0f;
  if constexpr (DO_LN) lw = lnw[lane];
  float ts = 1.0f;
  int cw = TDIM;
  if constexpr (IS_SQ) {
    const float tp = st->temp;
    ts = (tp > 0.0f ? rsqrtf(tp) : 1.0f) * 0.125f;   // fold 1/sqrt(64)
    cw = st->cw;
  }
  __syncthreads();
  const int rowBase = blockIdx.x * 32 + wv * 8;
  for (int rr = 0; rr < 8; ++rr) {
    const int row = rowBase + rr;
    if constexpr (IS_SQ) {
      if ((row & (TDIM - 1)) >= cw) continue;
    }
    const float h = in[(size_t)row * HD + lane];
    float y = bd;
#pragma unroll
    for (int i = 0; i < 64; ++i) {
      const float hv = __uint_as_float((unsigned)__builtin_amdgcn_readlane((int)__float_as_uint(h), i));
      y += wl[i * 65 + lane] * hv;
    }
    if constexpr (DO_LN) {
      float s = y;
#pragma unroll
      for (int off = 1; off < 64; off <<= 1) s += __shfl_xor(s, off);
      const float mean = s * (1.0f / 64.0f);
      const float t0 = y - mean;
      float v2 = t0 * t0;
#pragma unroll
      for (int off = 1; off < 64; off <<= 1) v2 += __shfl_xor(v2, off);
      y = t0 * rsqrtf(v2 * (1.0f / 64.0f) + 1e-5f) * lw;
    }
    if constexpr (IS_SQ) y *= ts;
    if constexpr (OUT_MODE == 0) {
      out[(size_t)row * HD + lane] = f2bf(y);
    } else {
      tT[lane * 34 + wv * 8 + rr] = f2bf(y);
    }
  }
  if constexpr (OUT_MODE == 1) {
    __syncthreads();
    const int hd = tid >> 2, tseg = (tid & 3) * 8;
    const int r0 = blockIdx.x * 32;
    const int bh = r0 >> 10, t0 = r0 & (TDIM - 1);
    short8v v;
#pragma unroll
    for (int i = 0; i < 8; ++i) v[i] = (short)tT[hd * 34 + tseg + i];
    *reinterpret_cast<short8v*>(out + ((size_t)bh * HD + hd) * TDIM + t0 + tseg) = v;
  }
}

// ---------------------------------------------------------------------------
// MFMA flash attention (bf16 inputs, fp32 softmax/accum). Unchanged from
// round 2 except the invalid-row epilogue stores explicit zeros.
// ---------------------------------------------------------------------------
__global__ __launch_bounds__(256) void attn_mfma_kernel(
    const unsigned short* __restrict__ sq, const unsigned short* __restrict__ sk,
    const unsigned short* __restrict__ vpT, float* __restrict__ io,
    const FState* __restrict__ st)
{
  if (st->done) return;
  const int cw = st->cw;
  const int bh = blockIdx.y;
  const int tid = threadIdx.x;
  const int wv = tid >> 6, lane = tid & 63;
  const int ql = lane & 15, hi = lane >> 4;
  const int qbase = blockIdx.x * 64 + wv * 16;
  const int q = qbase + ql;
  const size_t baseRow = (size_t)bh * TDIM * HD;
  const size_t baseT   = (size_t)bh * HD * TDIM;
  float* orow = io + baseRow + (size_t)q * HD;

  if (qbase >= cw) {
    const f32x4 z = {0.f, 0.f, 0.f, 0.f};
#pragma unroll
    for (int f = 0; f < 4; ++f)
      *reinterpret_cast<f32x4*>(orow + f * 16 + hi * 4) = z;
    return;
  }

  __shared__ __align__(16) unsigned char Plds[4 * 2048];
  unsigned char* P = Plds + wv * 2048;
  const unsigned swz = (unsigned)((ql & 7) << 4);

  short8v qf0, qf1;
  {
    const unsigned short* qp = sq + baseRow + (size_t)q * HD + hi * 8;
    qf0 = *reinterpret_cast<const short8v*>(qp);
    qf1 = *reinterpret_cast<const short8v*>(qp + 32);
  }

  float m = -1e30f, l = 0.f;
  f32x4 o[4] = {};
  const int nch = (cw + 63) >> 6;
  for (int ch = 0; ch < nch; ++ch) {
    const int k0 = ch * 64;
    f32x4 s[4];
#pragma unroll
    for (int f = 0; f < 4; ++f) {
      const unsigned short* kp = sk + baseRow + (size_t)(k0 + f * 16 + ql) * HD + hi * 8;
      const short8v a0 = *reinterpret_cast<const short8v*>(kp);
      const short8v a1 = *reinterpret_cast<const short8v*>(kp + 32);
      f32x4 acc = {};
      acc = __builtin_amdgcn_mfma_f32_16x16x32_bf16(a0, qf0, acc, 0, 0, 0);
      acc = __builtin_amdgcn_mfma_f32_16x16x32_bf16(a1, qf1, acc, 0, 0, 0);
      s[f] = acc;
    }
    float mc = -1e30f;
#pragma unroll
    for (int f = 0; f < 4; ++f) {
#pragma unroll
      for (int r = 0; r < 4; ++r) {
        float v = s[f][r];
        if (k0 + f * 16 + hi * 4 + r >= cw) v = -1e30f;
        s[f][r] = v;
        mc = fmaxf(mc, v);
      }
    }
    mc = fmaxf(mc, __shfl_xor(mc, 16));
    mc = fmaxf(mc, __shfl_xor(mc, 32));
    const float mn = fmaxf(m, mc);
    const float c = __builtin_amdgcn_exp2f((m - mn) * L2E);
    float ls = 0.f;
    unsigned pk[8];
#pragma unroll
    for (int f = 0; f < 4; ++f) {
      const float p0 = __builtin_amdgcn_exp2f((s[f][0] - mn) * L2E);
      const float p1 = __builtin_amdgcn_exp2f((s[f][1] - mn) * L2E);
      const float p2 = __builtin_amdgcn_exp2f((s[f][2] - mn) * L2E);
      const float p3 = __builtin_amdgcn_exp2f((s[f][3] - mn) * L2E);
      ls += (p0 + p1) + (p2 + p3);
      pk[f * 2]     = (unsigned)f2bf(p0) | ((unsigned)f2bf(p1) << 16);
      pk[f * 2 + 1] = (unsigned)f2bf(p2) | ((unsigned)f2bf(p3) << 16);
    }
    ls += __shfl_xor(ls, 16);
    ls += __shfl_xor(ls, 32);
    l = l * c + ls;
    m = mn;
#pragma unroll
    for (int f = 0; f < 4; ++f) o[f] *= c;
    const unsigned wb = (unsigned)(ql * 128 + hi * 8);
#pragma unroll
    for (int f = 0; f < 4; ++f) {
      *reinterpret_cast<unsigned*>(P + ((wb + f * 32)     ^ swz)) = pk[f * 2];
      *reinterpret_cast<unsigned*>(P + ((wb + f * 32 + 4) ^ swz)) = pk[f * 2 + 1];
    }
#pragma unroll
    for (int kh = 0; kh < 2; ++kh) {
      const short8v pb = *reinterpret_cast<short8v*>(
          P + ((unsigned)(ql * 128 + kh * 64 + hi * 16) ^ swz));
#pragma unroll
      for (int f = 0; f < 4; ++f) {
        const unsigned short* vp = vpT + baseT + (size_t)(f * 16 + ql) * TDIM + k0 + kh * 32 + hi * 8;
        const short8v av = *reinterpret_cast<const short8v*>(vp);
        o[f] = __builtin_amdgcn_mfma_f32_16x16x32_bf16(av, pb, o[f], 0, 0, 0);
      }
    }
  }
  const bool valid = (q < cw);
  if (valid) {
    const float invl = 1.0f / l;
#pragma unroll
    for (int f = 0; f < 4; ++f) {
      f32x4 vo = o[f] * invl;
      *reinterpret_cast<f32x4*>(orow + f * 16 + hi * 4) = vo;
    }
  } else {
    const f32x4 z = {0.f, 0.f, 0.f, 0.f};
#pragma unroll
    for (int f = 0; f < 4; ++f)
      *reinterpret_cast<f32x4*>(orow + f * 16 + hi * 4) = z;
  }
}

// ---------------------------------------------------------------------------
__global__ __launch_bounds__(256) void diff_kernel(
    const float* __restrict__ io, const float* __restrict__ prev,
    float* __restrict__ partials, const FState* __restrict__ st, int is_first)
{
  if (st->done) return;
  const int tid = threadIdx.x;
  const int gid = blockIdx.x * 256 + tid;
  float s = 0.0f;
  const float4* a = reinterpret_cast<const float4*>(io);
  const float4* b = reinterpret_cast<const float4*>(prev);
  for (int i = gid; i < NHE4; i += DIFF_BLOCKS * 256) {
    float4 v = a[i];
    if (!is_first) {
      const float4 p = b[i];
      v.x -= p.x; v.y -= p.y; v.z -= p.z; v.w -= p.w;
    }
    s += fabsf(v.x) + fabsf(v.y) + fabsf(v.z) + fabsf(v.w);
  }
#pragma unroll
  for (int off = 1; off < 64; off <<= 1) s += __shfl_xor(s, off);
  __shared__ float wsum[4];
  const int lane = tid & 63, wv = tid >> 6;
  if (lane == 0) wsum[wv] = s;
  __syncthreads();
  if (tid == 0) partials[blockIdx.x] = wsum[0] + wsum[1] + wsum[2] + wsum[3];
}

// ---------------------------------------------------------------------------
__global__ __launch_bounds__(256) void state_update_kernel(
    FState* __restrict__ st, const float* __restrict__ partials, int iter)
{
  const int tid = threadIdx.x;
  float s = 0.0f;
  for (int i = tid; i < DIFF_BLOCKS; i += 256) s += partials[i];
  __shared__ float red[256];
  red[tid] = s;
  __syncthreads();
  for (int off = 128; off > 0; off >>= 1) {
    if (tid < off) red[tid] += red[tid + off];
    __syncthreads();
  }
  if (tid == 0) {
    const int done_prev = st->done;
    st->done_prev = done_prev;
    if (!done_prev) {
      const float diff = red[0] * (1.0f / (float)NHE);
      const bool conv = (diff < st->thr + st->fac * diff) && (iter > 0);
      st->upd  = conv ? 0 : 1;
      st->done = conv ? 1 : 0;
      if (!conv) {
        const int cw = st->cw;
        const int up = (int)((float)cw * 1.1f);
        const int dn = (int)((float)cw * 0.9f);
        int nw = (diff > 0.05f) ? up : ((diff < 0.001f && cw > 64) ? dn : cw);
        nw = nw < 64 ? 64 : (nw > TDIM ? TDIM : nw);
        st->cw = nw;
        st->temp += 0.005f;
      }
    } else {
      st->upd = 0;
    }
  }
}

// ---------------------------------------------------------------------------
// carry update; also emits split-bf16 attn planes [2048][2048] (row-major
// gather from head layout) for the final MFMA GEMM.
// ---------------------------------------------------------------------------
__global__ __launch_bounds__(256) void update_kernel(
    const float* __restrict__ io, unsigned short* __restrict__ attnS,
    float* __restrict__ prev, float* __restrict__ qcur,
    const FState* __restrict__ st, int last)
{
  if (st->done_prev) return;
  const int upd = st->upd;
  const int i = blockIdx.x * 256 + threadIdx.x;
  if (i >= NHE4) return;
  const float4 v = reinterpret_cast<const float4*>(io)[i];
  // head layout float4 -> (bh, t, hd4)
  const int hd4 = i & 15;
  const int t   = (i >> 4) & (TDIM - 1);
  const int bh  = i >> 14;
  const int row = (bh >> 4) * TDIM + t;
  const int col = (bh & 15) * HD + hd4 * 4;
  const float vv[4] = { v.x, v.y, v.z, v.w };
  short4v h, l;
#pragma unroll
  for (int j = 0; j < 4; ++j) {
    const unsigned short hb = f2bf(vv[j]);
    h[j] = (short)hb;
    l[j] = (short)f2bf(vv[j] - bf2f(hb));
  }
  unsigned short* p = attnS + (size_t)row * 2048 + col;
  *reinterpret_cast<short4v*>(p) = h;
  *reinterpret_cast<short4v*>(p + 1024) = l;
  if (!last && upd) {
    reinterpret_cast<float4*>(prev)[i] = v;
    float4 qv = reinterpret_cast<float4*>(qcur)[i];
    qv.x += v.x; qv.y += v.y; qv.z += v.z; qv.w += v.w;
    reinterpret_cast<float4*>(qcur)[i] = qv;
  }
}

// ---------------------------------------------------------------------------
extern "C" void kernel_launch(void* const* d_in, const int* in_sizes, int n_in,
                              void* d_out, int out_size, void* d_ws, size_t ws_size,
                              hipStream_t stream)
{
  const float* x   = (const float*)d_in[0];
  const float* Wq  = (const float*)d_in[1];
  const float* bq  = (const float*)d_in[2];
  const float* Wk  = (const float*)d_in[3];
  const float* Wv  = (const float*)d_in[4];
  const float* bv  = (const float*)d_in[5];
  const float* Wo  = (const float*)d_in[6];
  const float* bo  = (const float*)d_in[7];
  const float* lna = (const float*)d_in[8];
  const float* lnb = (const float*)d_in[9];
  const float* lnc = (const float*)d_in[10];
  const float* lnd = (const float*)d_in[11];
  const float* lqw = (const float*)d_in[12];
  const float* lqb = (const float*)d_in[13];
  const float* lkw = (const float*)d_in[14];
  const float* lkb = (const float*)d_in[15];
  const float* lvw = (const float*)d_in[16];
  const float* lvb = (const float*)d_in[17];
  const float* thr = (const float*)d_in[18];
  const float* tb  = (const float*)d_in[19];
  const float* fac = (const float*)d_in[20];
  float* out = (float*)d_out;

  // workspace layout (~68 MB)
  float* f0   = (float*)d_ws;
  float* qcur = f0;                       // f32 head layout, 8MB
  float* io   = f0 + (size_t)NHE;         // f32, aliases ktmp
  float* prev = f0 + 2 * (size_t)NHE;     // f32, aliases vtmp
  unsigned short* u0    = (unsigned short*)(f0 + 3 * (size_t)NHE);
  unsigned short* xaS   = u0;                         // [2048][2048] hi|lo (aliases attnS)
  unsigned short* attnS = u0;
  unsigned short* xbS   = u0 + (size_t)4194304;
  unsigned short* WqS   = u0 + (size_t)8388608;       // [1024][2048] each
  unsigned short* WkS   = WqS + (size_t)2097152;
  unsigned short* WvS   = WkS + (size_t)2097152;
  unsigned short* WoS   = WvS + (size_t)2097152;
  unsigned short* sqb   = WoS + (size_t)2097152;      // bf16 [bh][t][hd]
  unsigned short* skb   = sqb + (size_t)NHE;
  unsigned short* vpT   = skb + (size_t)NHE;          // bf16 [bh][hd][t]
  float* partials = (float*)(vpT + (size_t)NHE);
  FState* st = (FState*)(partials + DIFF_BLOCKS);

  constexpr float SC = 0.35355339059327379f;  // 64^-0.25

  hipLaunchKernelGGL(init_kernel, dim3(1), dim3(64), 0, stream, st, thr, tb, fac);
  hipLaunchKernelGGL(ln_x_kernel, dim3(RROWS), dim3(256), 0, stream, x, lna, lnb, xaS, xbS);
  hipLaunchKernelGGL(w_split_kernel, dim3(1024, 4), dim3(256), 0, stream,
                     Wq, Wk, Wv, Wo, WqS, WkS, WvS, WoS);

  // fused QKV split-bf16 MFMA GEMMs -> f32 head layouts (qcur, io=k, prev=v)
  hipLaunchKernelGGL((gemm_mfma_kernel<1>), dim3(16, 8, 3), dim3(256), 0, stream,
                     xaS, WqS, bq, qcur, SC,
                     xbS, WkS, (const float*)nullptr, io, SC,
                     xbS, WvS, bv, prev, 1.0f);

  // iteration-invariant head projections
  hipLaunchKernelGGL((headproj_kernel<0, true, false>), dim3(1024), dim3(256), 0, stream,
                     io, skb, lkw, lkb, lnd, (const FState*)nullptr);
  hipLaunchKernelGGL((headproj_kernel<1, false, false>), dim3(1024), dim3(256), 0, stream,
                     prev, vpT, lvw, lvb, (const float*)nullptr, (const FState*)nullptr);

  for (int it = 0; it < 3; ++it) {
    hipLaunchKernelGGL((headproj_kernel<0, true, true>), dim3(1024), dim3(256), 0, stream,
                       qcur, sqb, lqw, lqb, lnc, st);
    hipLaunchKernelGGL(attn_mfma_kernel, dim3(16, BH), dim3(256), 0, stream,
                       sqb, skb, vpT, io, st);
    hipLaunchKernelGGL(diff_kernel, dim3(DIFF_BLOCKS), dim3(256), 0, stream,
                       io, prev, partials, st, it == 0 ? 1 : 0);
    hipLaunchKernelGGL(state_update_kernel, dim3(1), dim3(256), 0, stream,
                       st, partials, it);
    hipLaunchKernelGGL(update_kernel, dim3(NHE4 / 256), dim3(256), 0, stream,
                       io, attnS, prev, qcur, st, it == 2 ? 1 : 0);
  }

  // final split-bf16 MFMA GEMM: out = attn @ Wo^T + bo (row-major f32)
  hipLaunchKernelGGL((gemm_mfma_kernel<0>), dim3(16, 8, 1), dim3(256), 0, stream,
                     attnS, WoS, bo, out, 1.0f,
                     attnS, WoS, bo, out, 1.0f,
                     attnS, WoS, bo, out, 1.0f);
}

// Round 4
// 280.547 us; speedup vs baseline: 4.2008x; 1.3202x over previous
//
#include <hip/hip_runtime.h>
#include <hip/hip_bf16.h>

// Sizes (fixed by the reference)
#define BDIM 2
#define TDIM 1024
#define DDIM 1024
#define HDIM 16
#define HD   64
#define RROWS (BDIM * TDIM)        // 2048 rows for the big GEMMs
#define BH    (BDIM * HDIM)        // 32 (b,h) pairs
#define NHE   (BH * TDIM * HD)     // 2,097,152 elements in head layout
#define NHE4  (NHE / 4)
#define DIFF_BLOCKS 512            // = attn grid (16 x 32)
#define L2E 1.4426950408889634f

typedef __attribute__((ext_vector_type(8))) short short8v;
typedef __attribute__((ext_vector_type(4))) short short4v;
typedef __attribute__((ext_vector_type(8))) _Float16 half8v;
typedef __attribute__((ext_vector_type(4))) _Float16 half4v;
typedef __attribute__((ext_vector_type(4))) float f32x4;

struct FState {
  int   cw;
  float temp;
  int   done;
  int   upd;
  int   done_prev;
  float thr;
  float fac;
  int   pad;
};

static __device__ __forceinline__ unsigned short f2bf(float x) {
  __hip_bfloat16 h = __float2bfloat16(x);
  return __builtin_bit_cast(unsigned short, h);
}
// async global->LDS, 16B per lane. LDS dest is wave-uniform base (+lane*16 by HW).
static __device__ __forceinline__ void gload16(const void* g, void* l) {
  __builtin_amdgcn_global_load_lds(
      (const __attribute__((address_space(1))) void*)g,
      (__attribute__((address_space(3))) void*)l, 16, 0, 0);
}

// ---------------------------------------------------------------------------
__global__ void init_kernel(FState* st, const float* thr, const float* tb, const float* fac) {
  if (threadIdx.x == 0 && blockIdx.x == 0) {
    st->cw = TDIM;
    st->temp = tb[0];
    st->done = 0;
    st->done_prev = 0;
    st->upd = 1;
    st->thr = thr[0];
    st->fac = fac[0];
  }
}

// ---------------------------------------------------------------------------
// LayerNorm of x with two weight vectors (shared mean/var) -> fp16 [2048][1024]
// ---------------------------------------------------------------------------
__global__ __launch_bounds__(256) void ln_x_kernel(
    const float* __restrict__ x, const float* __restrict__ wa, const float* __restrict__ wb,
    _Float16* __restrict__ xaH, _Float16* __restrict__ xbH)
{
  const int row = blockIdx.x;
  const int tid = threadIdx.x;
  const float4 v = reinterpret_cast<const float4*>(x + (size_t)row * DDIM)[tid];
  float s = v.x + v.y + v.z + v.w;
  float q = v.x * v.x + v.y * v.y + v.z * v.z + v.w * v.w;
#pragma unroll
  for (int off = 1; off < 64; off <<= 1) {
    s += __shfl_xor(s, off);
    q += __shfl_xor(q, off);
  }
  __shared__ float ss[4], qq[4];
  const int lane = tid & 63, wv = tid >> 6;
  if (lane == 0) { ss[wv] = s; qq[wv] = q; }
  __syncthreads();
  s = ss[0] + ss[1] + ss[2] + ss[3];
  q = qq[0] + qq[1] + qq[2] + qq[3];
  const float mean = s * (1.0f / DDIM);
  const float var  = q * (1.0f / DDIM) - mean * mean;
  const float inv  = rsqrtf(var + 1e-5f);
  const float4 a4 = reinterpret_cast<const float4*>(wa)[tid];
  const float4 b4 = reinterpret_cast<const float4*>(wb)[tid];
  const float hv[4] = { (v.x - mean) * inv, (v.y - mean) * inv,
                        (v.z - mean) * inv, (v.w - mean) * inv };
  const float av[4] = { a4.x, a4.y, a4.z, a4.w };
  const float bv[4] = { b4.x, b4.y, b4.z, b4.w };
  half4v ha, hb;
#pragma unroll
  for (int j = 0; j < 4; ++j) {
    ha[j] = (_Float16)(hv[j] * av[j]);
    hb[j] = (_Float16)(hv[j] * bv[j]);
  }
  *reinterpret_cast<half4v*>(xaH + (size_t)row * DDIM + tid * 4) = ha;
  *reinterpret_cast<half4v*>(xbH + (size_t)row * DDIM + tid * 4) = hb;
}

// ---------------------------------------------------------------------------
// convert the 4 weight matrices [1024][1024] f32 -> fp16
// ---------------------------------------------------------------------------
__global__ __launch_bounds__(256) void w_cvt_kernel(
    const float* __restrict__ W0, const float* __restrict__ W1,
    const float* __restrict__ W2, const float* __restrict__ W3,
    _Float16* __restrict__ O0, _Float16* __restrict__ O1,
    _Float16* __restrict__ O2, _Float16* __restrict__ O3)
{
  const float* W; _Float16* O;
  switch (blockIdx.y) {
    case 0:  W = W0; O = O0; break;
    case 1:  W = W1; O = O1; break;
    case 2:  W = W2; O = O2; break;
    default: W = W3; O = O3; break;
  }
  const int r = blockIdx.x;
  const int tid = threadIdx.x;
  const float4 v = reinterpret_cast<const float4*>(W + (size_t)r * 1024)[tid];
  half4v h;
  h[0] = (_Float16)v.x; h[1] = (_Float16)v.y;
  h[2] = (_Float16)v.z; h[3] = (_Float16)v.w;
  *reinterpret_cast<half4v*>(O + (size_t)r * 1024 + tid * 4) = h;
}

// ---------------------------------------------------------------------------
// fp16 MFMA GEMM: C = (A @ W^T + bias) * scale, fp32 accumulation.
// A [2048][1024] fp16, W [1024][1024] fp16 row-major (we need W[n][k]).
// 128x128 tile, BK=32, 4 waves (2x2), 4x4 16x16x32 frags per wave.
// Staging via global_load_lds dwordx4, linear LDS, 2-barrier loop.
// CMODE 0: C row-major f32. CMODE 1: C scattered to head layout [B,H,T,64].
// blockIdx.z selects one of up to 3 fused GEMMs.
// ---------------------------------------------------------------------------
template<int CMODE>
__global__ __launch_bounds__(256) void gemm_mfma_kernel(
    const _Float16* __restrict__ A0, const _Float16* __restrict__ W0,
    const float* __restrict__ b0, float* __restrict__ C0, float s0,
    const _Float16* __restrict__ A1, const _Float16* __restrict__ W1,
    const float* __restrict__ b1, float* __restrict__ C1, float s1,
    const _Float16* __restrict__ A2, const _Float16* __restrict__ W2,
    const float* __restrict__ b2, float* __restrict__ C2, float s2)
{
  const _Float16* A; const _Float16* W; const float* bias; float* C; float scale;
  switch (blockIdx.z) {
    case 0:  A = A0; W = W0; bias = b0; C = C0; scale = s0; break;
    case 1:  A = A1; W = W1; bias = b1; C = C1; scale = s1; break;
    default: A = A2; W = W2; bias = b2; C = C2; scale = s2; break;
  }
  __shared__ __align__(16) _Float16 As[128 * 32];
  __shared__ __align__(16) _Float16 Ws[128 * 32];
  const int tid = threadIdx.x;
  const int wv = tid >> 6, lane = tid & 63;
  const int wm = wv >> 1, wn = wv & 1;
  const int bm = blockIdx.x;           // 16 M-blocks
  const int bn = blockIdx.y;           // 8 N-blocks

  // staging: wave wv covers chunks j=0,1 of 16 rows; lane -> row lane>>2,
  // 16B col (lane&3)*16 within the 64B k-row. LDS dest linear row-major.
  const _Float16* gA[2]; const _Float16* gW[2];
  _Float16* lA[2]; _Float16* lW[2];
#pragma unroll
  for (int j = 0; j < 2; ++j) {
    const int chunk = wv * 2 + j;                  // 0..7
    const int r = chunk * 16 + (lane >> 2);
    const int ce = (lane & 3) * 8;                 // element col within 32
    gA[j] = A + (size_t)(bm * 128 + r) * 1024 + ce;
    gW[j] = W + (size_t)(bn * 128 + r) * 1024 + ce;
    lA[j] = As + chunk * 512;                      // wave-uniform base
    lW[j] = Ws + chunk * 512;
  }

  f32x4 acc[4][4] = {};
  const int rb = lane & 15;
  const int kb = (lane >> 4) * 8;

  for (int ks = 0; ks < 1024; ks += 32) {
    __syncthreads();
#pragma unroll
    for (int j = 0; j < 2; ++j) {
      gload16(gA[j] + ks, lA[j]);
      gload16(gW[j] + ks, lW[j]);
    }
    __syncthreads();
    half8v af[4], wf[4];
#pragma unroll
    for (int f = 0; f < 4; ++f) {
      af[f] = *reinterpret_cast<const half8v*>(As + (wm * 64 + f * 16 + rb) * 32 + kb);
      wf[f] = *reinterpret_cast<const half8v*>(Ws + (wn * 64 + f * 16 + rb) * 32 + kb);
    }
#pragma unroll
    for (int i = 0; i < 4; ++i)
#pragma unroll
      for (int j2 = 0; j2 < 4; ++j2)
        acc[i][j2] = __builtin_amdgcn_mfma_f32_16x16x32_f16(af[i], wf[j2], acc[i][j2], 0, 0, 0);
  }

  // epilogue: D col = lane&15 -> n, row = (lane>>4)*4 + r -> m
#pragma unroll
  for (int j2 = 0; j2 < 4; ++j2) {
    const int n = bn * 128 + wn * 64 + j2 * 16 + (lane & 15);
    const float bv_ = bias ? bias[n] : 0.0f;
#pragma unroll
    for (int i = 0; i < 4; ++i) {
#pragma unroll
      for (int r = 0; r < 4; ++r) {
        const int m = bm * 128 + wm * 64 + i * 16 + (lane >> 4) * 4 + r;
        const float v = (acc[i][j2][r] + bv_) * scale;
        size_t ci;
        if constexpr (CMODE == 0) {
          ci = (size_t)m * 1024 + n;
        } else {
          const int b = m >> 10, t = m & (TDIM - 1);
          ci = ((size_t)(b * HDIM + (n >> 6)) * TDIM + t) * HD + (n & 63);
        }
        C[ci] = v;
      }
    }
  }
}

// ---------------------------------------------------------------------------
// per-head 64x64 projection -> bf16 outputs for the MFMA attention.
// OUT_MODE 0: bf16 [t][hd]. OUT_MODE 1: bf16 transposed [hd][t]. IS_SQ: gate
// on done, skip rows >= cw, fold tscale * 1/sqrt(64).
// ---------------------------------------------------------------------------
template<int OUT_MODE, bool DO_LN, bool IS_SQ>
__global__ __launch_bounds__(256) void headproj_kernel(
    const float* __restrict__ in, unsigned short* __restrict__ out,
    const float* __restrict__ w, const float* __restrict__ bias,
    const float* __restrict__ lnw, const FState* __restrict__ st)
{
  if constexpr (IS_SQ) { if (st->done) return; }
  __shared__ float wl[64 * 65];
  __shared__ unsigned short tT[64 * 34];
  const int tid = threadIdx.x;
  for (int idx = tid; idx < 4096; idx += 256) {
    const int d = idx >> 6, i = idx & 63;
    wl[i * 65 + d] = w[idx];
  }
  const int lane = tid & 63, wv = tid >> 6;
  const float bd = bias[lane];
  float lw = 1.0f;
  if constexpr (DO_LN) lw = lnw[lane];
  float ts = 1.0f;
  int cw = TDIM;
  if constexpr (IS_SQ) {
    const float tp = st->temp;
    ts = (tp > 0.0f ? rsqrtf(tp) : 1.0f) * 0.125f;   // fold 1/sqrt(64)
    cw = st->cw;
  }
  __syncthreads();
  const int rowBase = blockIdx.x * 32 + wv * 8;
  for (int rr = 0; rr < 8; ++rr) {
    const int row = rowBase + rr;
    if constexpr (IS_SQ) {
      if ((row & (TDIM - 1)) >= cw) continue;
    }
    const float h = in[(size_t)row * HD + lane];
    float y = bd;
#pragma unroll
    for (int i = 0; i < 64; ++i) {
      const float hv = __uint_as_float((unsigned)__builtin_amdgcn_readlane((int)__float_as_uint(h), i));
      y += wl[i * 65 + lane] * hv;
    }
    if constexpr (DO_LN) {
      float s = y;
#pragma unroll
      for (int off = 1; off < 64; off <<= 1) s += __shfl_xor(s, off);
      const float mean = s * (1.0f / 64.0f);
      const float t0 = y - mean;
      float v2 = t0 * t0;
#pragma unroll
      for (int off = 1; off < 64; off <<= 1) v2 += __shfl_xor(v2, off);
      y = t0 * rsqrtf(v2 * (1.0f / 64.0f) + 1e-5f) * lw;
    }
    if constexpr (IS_SQ) y *= ts;
    if constexpr (OUT_MODE == 0) {
      out[(size_t)row * HD + lane] = f2bf(y);
    } else {
      tT[lane * 34 + wv * 8 + rr] = f2bf(y);
    }
  }
  if constexpr (OUT_MODE == 1) {
    __syncthreads();
    const int hd = tid >> 2, tseg = (tid & 3) * 8;
    const int r0 = blockIdx.x * 32;
    const int bh = r0 >> 10, t0 = r0 & (TDIM - 1);
    short8v v;
#pragma unroll
    for (int i = 0; i < 8; ++i) v[i] = (short)tT[hd * 34 + tseg + i];
    *reinterpret_cast<short8v*>(out + ((size_t)bh * HD + hd) * TDIM + t0 + tseg) = v;
  }
}

// ---------------------------------------------------------------------------
// MFMA flash attention (bf16 inputs, fp32 softmax/accum) with FUSED diff:
// each block also computes sum |io - prev| over its rows -> partials.
// Block = 4 waves; wave owns 16 q-rows. Swapped QK^T; P^ via per-wave
// swizzled LDS; PV via pre-transposed V. No barriers in the k-loop.
// ---------------------------------------------------------------------------
__global__ __launch_bounds__(256) void attn_mfma_kernel(
    const unsigned short* __restrict__ sq, const unsigned short* __restrict__ sk,
    const unsigned short* __restrict__ vpT, float* __restrict__ io,
    const float* __restrict__ prev, float* __restrict__ partials,
    const FState* __restrict__ st, int is_first)
{
  if (st->done) return;
  const int cw = st->cw;
  const int bh = blockIdx.y;
  const int tid = threadIdx.x;
  const int wv = tid >> 6, lane = tid & 63;
  const int ql = lane & 15, hi = lane >> 4;
  const int qbase = blockIdx.x * 64 + wv * 16;
  const int q = qbase + ql;
  const size_t baseRow = (size_t)bh * TDIM * HD;
  const size_t baseT   = (size_t)bh * HD * TDIM;
  float* orow = io + baseRow + (size_t)q * HD;
  const float* prow = prev + baseRow + (size_t)q * HD;

  __shared__ __align__(16) unsigned char Plds[4 * 2048];
  float pd = 0.0f;

  if (qbase >= cw) {
    const f32x4 z = {0.f, 0.f, 0.f, 0.f};
#pragma unroll
    for (int f = 0; f < 4; ++f) {
      *reinterpret_cast<f32x4*>(orow + f * 16 + hi * 4) = z;
      if (!is_first) {
        const f32x4 pv = *reinterpret_cast<const f32x4*>(prow + f * 16 + hi * 4);
        pd += fabsf(pv[0]) + fabsf(pv[1]) + fabsf(pv[2]) + fabsf(pv[3]);
      }
    }
  } else {
    unsigned char* P = Plds + wv * 2048;
    const unsigned swz = (unsigned)((ql & 7) << 4);

    short8v qf0, qf1;
    {
      const unsigned short* qp = sq + baseRow + (size_t)q * HD + hi * 8;
      qf0 = *reinterpret_cast<const short8v*>(qp);
      qf1 = *reinterpret_cast<const short8v*>(qp + 32);
    }

    float m = -1e30f, l = 0.f;
    f32x4 o[4] = {};
    const int nch = (cw + 63) >> 6;
    for (int ch = 0; ch < nch; ++ch) {
      const int k0 = ch * 64;
      f32x4 s[4];
#pragma unroll
      for (int f = 0; f < 4; ++f) {
        const unsigned short* kp = sk + baseRow + (size_t)(k0 + f * 16 + ql) * HD + hi * 8;
        const short8v a0 = *reinterpret_cast<const short8v*>(kp);
        const short8v a1 = *reinterpret_cast<const short8v*>(kp + 32);
        f32x4 acc = {};
        acc = __builtin_amdgcn_mfma_f32_16x16x32_bf16(a0, qf0, acc, 0, 0, 0);
        acc = __builtin_amdgcn_mfma_f32_16x16x32_bf16(a1, qf1, acc, 0, 0, 0);
        s[f] = acc;
      }
      float mc = -1e30f;
#pragma unroll
      for (int f = 0; f < 4; ++f) {
#pragma unroll
        for (int r = 0; r < 4; ++r) {
          float v = s[f][r];
          if (k0 + f * 16 + hi * 4 + r >= cw) v = -1e30f;
          s[f][r] = v;
          mc = fmaxf(mc, v);
        }
      }
      mc = fmaxf(mc, __shfl_xor(mc, 16));
      mc = fmaxf(mc, __shfl_xor(mc, 32));
      const float mn = fmaxf(m, mc);
      const float c = __builtin_amdgcn_exp2f((m - mn) * L2E);
      float ls = 0.f;
      unsigned pk[8];
#pragma unroll
      for (int f = 0; f < 4; ++f) {
        const float p0 = __builtin_amdgcn_exp2f((s[f][0] - mn) * L2E);
        const float p1 = __builtin_amdgcn_exp2f((s[f][1] - mn) * L2E);
        const float p2 = __builtin_amdgcn_exp2f((s[f][2] - mn) * L2E);
        const float p3 = __builtin_amdgcn_exp2f((s[f][3] - mn) * L2E);
        ls += (p0 + p1) + (p2 + p3);
        pk[f * 2]     = (unsigned)f2bf(p0) | ((unsigned)f2bf(p1) << 16);
        pk[f * 2 + 1] = (unsigned)f2bf(p2) | ((unsigned)f2bf(p3) << 16);
      }
      ls += __shfl_xor(ls, 16);
      ls += __shfl_xor(ls, 32);
      l = l * c + ls;
      m = mn;
#pragma unroll
      for (int f = 0; f < 4; ++f) o[f] *= c;
      const unsigned wb = (unsigned)(ql * 128 + hi * 8);
#pragma unroll
      for (int f = 0; f < 4; ++f) {
        *reinterpret_cast<unsigned*>(P + ((wb + f * 32)     ^ swz)) = pk[f * 2];
        *reinterpret_cast<unsigned*>(P + ((wb + f * 32 + 4) ^ swz)) = pk[f * 2 + 1];
      }
#pragma unroll
      for (int kh = 0; kh < 2; ++kh) {
        const short8v pb = *reinterpret_cast<short8v*>(
            P + ((unsigned)(ql * 128 + kh * 64 + hi * 16) ^ swz));
#pragma unroll
        for (int f = 0; f < 4; ++f) {
          const unsigned short* vp = vpT + baseT + (size_t)(f * 16 + ql) * TDIM + k0 + kh * 32 + hi * 8;
          const short8v av = *reinterpret_cast<const short8v*>(vp);
          o[f] = __builtin_amdgcn_mfma_f32_16x16x32_bf16(av, pb, o[f], 0, 0, 0);
        }
      }
    }
    const bool valid = (q < cw);
    const float invl = valid ? (1.0f / l) : 0.0f;
#pragma unroll
    for (int f = 0; f < 4; ++f) {
      const f32x4 vo = o[f] * invl;
      *reinterpret_cast<f32x4*>(orow + f * 16 + hi * 4) = vo;
      if (!is_first) {
        const f32x4 pv = *reinterpret_cast<const f32x4*>(prow + f * 16 + hi * 4);
        pd += fabsf(vo[0] - pv[0]) + fabsf(vo[1] - pv[1]) +
              fabsf(vo[2] - pv[2]) + fabsf(vo[3] - pv[3]);
      } else {
        pd += fabsf(vo[0]) + fabsf(vo[1]) + fabsf(vo[2]) + fabsf(vo[3]);
      }
    }
  }

  // block-wide diff reduction -> partials[by*16 + bx]
#pragma unroll
  for (int off = 1; off < 64; off <<= 1) pd += __shfl_xor(pd, off);
  __shared__ float wred[4];
  if (lane == 0) wred[wv] = pd;
  __syncthreads();
  if (tid == 0)
    partials[blockIdx.y * 16 + blockIdx.x] = wred[0] + wred[1] + wred[2] + wred[3];
}

// ---------------------------------------------------------------------------
__global__ __launch_bounds__(256) void state_update_kernel(
    FState* __restrict__ st, const float* __restrict__ partials, int iter)
{
  const int tid = threadIdx.x;
  float s = partials[tid] + partials[tid + 256];
  __shared__ float red[256];
  red[tid] = s;
  __syncthreads();
  for (int off = 128; off > 0; off >>= 1) {
    if (tid < off) red[tid] += red[tid + off];
    __syncthreads();
  }
  if (tid == 0) {
    const int done_prev = st->done;
    st->done_prev = done_prev;
    if (!done_prev) {
      const float diff = red[0] * (1.0f / (float)NHE);
      const bool conv = (diff < st->thr + st->fac * diff) && (iter > 0);
      st->upd  = conv ? 0 : 1;
      st->done = conv ? 1 : 0;
      if (!conv) {
        const int cw = st->cw;
        const int up = (int)((float)cw * 1.1f);
        const int dn = (int)((float)cw * 0.9f);
        int nw = (diff > 0.05f) ? up : ((diff < 0.001f && cw > 64) ? dn : cw);
        nw = nw < 64 ? 64 : (nw > TDIM ? TDIM : nw);
        st->cw = nw;
        st->temp += 0.005f;
      }
    } else {
      st->upd = 0;
    }
  }
}

// ---------------------------------------------------------------------------
// carry update; emits fp16 attn [2048][1024] (row-major gather from head
// layout) for the final MFMA GEMM.
// ---------------------------------------------------------------------------
__global__ __launch_bounds__(256) void update_kernel(
    const float* __restrict__ io, _Float16* __restrict__ attnH,
    float* __restrict__ prev, float* __restrict__ qcur,
    const FState* __restrict__ st, int last)
{
  if (st->done_prev) return;
  const int upd = st->upd;
  const int i = blockIdx.x * 256 + threadIdx.x;
  if (i >= NHE4) return;
  const float4 v = reinterpret_cast<const float4*>(io)[i];
  // head layout float4 -> (bh, t, hd4)
  const int hd4 = i & 15;
  const int t   = (i >> 4) & (TDIM - 1);
  const int bh  = i >> 14;
  const int row = (bh >> 4) * TDIM + t;
  const int col = (bh & 15) * HD + hd4 * 4;
  half4v h;
  h[0] = (_Float16)v.x; h[1] = (_Float16)v.y;
  h[2] = (_Float16)v.z; h[3] = (_Float16)v.w;
  *reinterpret_cast<half4v*>(attnH + (size_t)row * 1024 + col) = h;
  if (!last && upd) {
    reinterpret_cast<float4*>(prev)[i] = v;
    float4 qv = reinterpret_cast<float4*>(qcur)[i];
    qv.x += v.x; qv.y += v.y; qv.z += v.z; qv.w += v.w;
    reinterpret_cast<float4*>(qcur)[i] = qv;
  }
}

// ---------------------------------------------------------------------------
extern "C" void kernel_launch(void* const* d_in, const int* in_sizes, int n_in,
                              void* d_out, int out_size, void* d_ws, size_t ws_size,
                              hipStream_t stream)
{
  const float* x   = (const float*)d_in[0];
  const float* Wq  = (const float*)d_in[1];
  const float* bq  = (const float*)d_in[2];
  const float* Wk  = (const float*)d_in[3];
  const float* Wv  = (const float*)d_in[4];
  const float* bv  = (const float*)d_in[5];
  const float* Wo  = (const float*)d_in[6];
  const float* bo  = (const float*)d_in[7];
  const float* lna = (const float*)d_in[8];
  const float* lnb = (const float*)d_in[9];
  const float* lnc = (const float*)d_in[10];
  const float* lnd = (const float*)d_in[11];
  const float* lqw = (const float*)d_in[12];
  const float* lqb = (const float*)d_in[13];
  const float* lkw = (const float*)d_in[14];
  const float* lkb = (const float*)d_in[15];
  const float* lvw = (const float*)d_in[16];
  const float* lvb = (const float*)d_in[17];
  const float* thr = (const float*)d_in[18];
  const float* tb  = (const float*)d_in[19];
  const float* fac = (const float*)d_in[20];
  float* out = (float*)d_out;

  // workspace layout (~56 MB)
  float* f0   = (float*)d_ws;
  float* qcur = f0;                       // f32 head layout, 8MB
  float* io   = f0 + (size_t)NHE;         // f32 (k-heads, then iter_out)
  float* prev = f0 + 2 * (size_t)NHE;     // f32 (v-heads, then prev)
  _Float16* h0   = (_Float16*)(f0 + 3 * (size_t)NHE);
  _Float16* xaH  = h0;                         // [2048][1024] fp16 (aliases attnH)
  _Float16* attnH = h0;
  _Float16* xbH  = h0 + (size_t)RROWS * 1024;
  _Float16* WqH  = xbH + (size_t)RROWS * 1024; // [1024][1024] fp16 each
  _Float16* WkH  = WqH + (size_t)1048576;
  _Float16* WvH  = WkH + (size_t)1048576;
  _Float16* WoH  = WvH + (size_t)1048576;
  unsigned short* sqb = (unsigned short*)(WoH + (size_t)1048576); // bf16 [bh][t][hd]
  unsigned short* skb = sqb + (size_t)NHE;
  unsigned short* vpT = skb + (size_t)NHE;     // bf16 [bh][hd][t]
  float* partials = (float*)(vpT + (size_t)NHE);
  FState* st = (FState*)(partials + DIFF_BLOCKS);

  constexpr float SC = 0.35355339059327379f;  // 64^-0.25

  hipLaunchKernelGGL(init_kernel, dim3(1), dim3(64), 0, stream, st, thr, tb, fac);
  hipLaunchKernelGGL(ln_x_kernel, dim3(RROWS), dim3(256), 0, stream, x, lna, lnb, xaH, xbH);
  hipLaunchKernelGGL(w_cvt_kernel, dim3(1024, 4), dim3(256), 0, stream,
                     Wq, Wk, Wv, Wo, WqH, WkH, WvH, WoH);

  // fused QKV fp16 MFMA GEMMs -> f32 head layouts (qcur, io=k, prev=v)
  hipLaunchKernelGGL((gemm_mfma_kernel<1>), dim3(16, 8, 3), dim3(256), 0, stream,
                     xaH, WqH, bq, qcur, SC,
                     xbH, WkH, (const float*)nullptr, io, SC,
                     xbH, WvH, bv, prev, 1.0f);

  // iteration-invariant head projections
  hipLaunchKernelGGL((headproj_kernel<0, true, false>), dim3(1024), dim3(256), 0, stream,
                     io, skb, lkw, lkb, lnd, (const FState*)nullptr);
  hipLaunchKernelGGL((headproj_kernel<1, false, false>), dim3(1024), dim3(256), 0, stream,
                     prev, vpT, lvw, lvb, (const float*)nullptr, (const FState*)nullptr);

  for (int it = 0; it < 3; ++it) {
    hipLaunchKernelGGL((headproj_kernel<0, true, true>), dim3(1024), dim3(256), 0, stream,
                       qcur, sqb, lqw, lqb, lnc, st);
    hipLaunchKernelGGL(attn_mfma_kernel, dim3(16, BH), dim3(256), 0, stream,
                       sqb, skb, vpT, io, prev, partials, st, it == 0 ? 1 : 0);
    hipLaunchKernelGGL(state_update_kernel, dim3(1), dim3(256), 0, stream,
                       st, partials, it);
    hipLaunchKernelGGL(update_kernel, dim3(NHE4 / 256), dim3(256), 0, stream,
                       io, attnH, prev, qcur, st, it == 2 ? 1 : 0);
  }

  // final fp16 MFMA GEMM: out = attn @ Wo^T + bo (row-major f32)
  hipLaunchKernelGGL((gemm_mfma_kernel<0>), dim3(16, 8, 1), dim3(256), 0, stream,
                     attnH, WoH, bo, out, 1.0f,
                     attnH, WoH, bo, out, 1.0f,
                     attnH, WoH, bo, out, 1.0f);
}